// Round 1
// baseline (87111.328 us; speedup 1.0000x reference)
//
#include <hip/hip_runtime.h>
#include <math.h>

#define VOCAB 8000
#define DIM 512
#define NLAYER 8
#define NHEAD 8
#define BATCH 16
#define TMAX 80
#define PROMPT_LEN 64
#define NNEW 16
#define HEADD 64
#define ATT_SCALE 0.125f

__device__ __forceinline__ float gelu_f(float x) {
  return 0.5f * x * (1.0f + tanhf(0.7978845608028654f * (x + 0.044715f * x * x * x)));
}

// ---------------- init ----------------
__global__ void k_init(const int* __restrict__ ids_in, const int* __restrict__ mask_in,
                       int* __restrict__ ids, int* __restrict__ lens, int* __restrict__ fin,
                       float* __restrict__ csum, float* __restrict__ ccnt) {
  int tid = threadIdx.x;
  for (int i = tid; i < BATCH * TMAX; i += blockDim.x) ids[i] = ids_in[i];
  if (tid < BATCH) {
    int s = 0;
    for (int t = 0; t < TMAX; ++t) s += mask_in[tid * TMAX + t];
    lens[tid] = s;
    fin[tid] = 0;
    csum[tid] = 0.f;
    ccnt[tid] = 0.f;
  }
}

// ---------------- embedding ----------------
__global__ void k_embed_prefill(const int* __restrict__ ids, const float* __restrict__ wte,
                                const float* __restrict__ wpe, float* __restrict__ x) {
  int bt = blockIdx.x;
  int b = bt / PROMPT_LEN, t = bt % PROMPT_LEN;
  int tok = ids[b * TMAX + t];
  for (int d = threadIdx.x; d < DIM; d += blockDim.x)
    x[(size_t)bt * DIM + d] = wte[(size_t)tok * DIM + d] + wpe[(size_t)t * DIM + d];
}

__global__ void k_embed_decode(const int* __restrict__ ids, const int* __restrict__ lens,
                               const float* __restrict__ wte, const float* __restrict__ wpe,
                               float* __restrict__ xd) {
  int b = blockIdx.x;
  int p = lens[b] - 1;
  if (p < 0) p = 0;
  if (p > TMAX - 1) p = TMAX - 1;
  int tok = ids[b * TMAX + p];
  for (int d = threadIdx.x; d < DIM; d += blockDim.x)
    xd[(size_t)b * DIM + d] = wte[(size_t)tok * DIM + d] + wpe[(size_t)p * DIM + d];
}

// ---------------- layernorm (one block of 256 per row of 512) ----------------
__global__ void k_layernorm(const float* __restrict__ x, const float* __restrict__ w,
                            const float* __restrict__ b, float* __restrict__ out) {
  int row = blockIdx.x;
  int tid = threadIdx.x;
  const float* xr = x + (size_t)row * DIM;
  __shared__ float red[256];
  float v0 = xr[tid], v1 = xr[tid + 256];
  red[tid] = v0 + v1;
  __syncthreads();
  for (int s = 128; s > 0; s >>= 1) {
    if (tid < s) red[tid] += red[tid + s];
    __syncthreads();
  }
  float mean = red[0] * (1.0f / DIM);
  __syncthreads();
  float d0 = v0 - mean, d1 = v1 - mean;
  red[tid] = d0 * d0 + d1 * d1;
  __syncthreads();
  for (int s = 128; s > 0; s >>= 1) {
    if (tid < s) red[tid] += red[tid + s];
    __syncthreads();
  }
  float rstd = 1.0f / sqrtf(red[0] * (1.0f / DIM) + 1e-5f);
  out[(size_t)row * DIM + tid] = d0 * rstd * w[tid] + b[tid];
  out[(size_t)row * DIM + tid + 256] = d1 * rstd * w[tid + 256] + b[tid + 256];
}

// ---------------- tiled fp32 GEMM: C[M,N] = A[M,K] @ W[K,N] (+bias)(+res)(gelu) ----------------
// MODE: 0 = plain, 1 = gelu(out), 2 = out += res
template <int MODE>
__global__ __launch_bounds__(256) void gemm_kernel(const float* __restrict__ A,
                                                   const float* __restrict__ W,
                                                   const float* __restrict__ bias,
                                                   const float* __restrict__ res,
                                                   float* __restrict__ C, int M, int N, int K) {
  const int BM = 64, BN = 64, BK = 16;
  __shared__ float As[BK][BM + 1];
  __shared__ float Ws[BK][BN];
  int tid = threadIdx.x;
  int bm = blockIdx.y * BM, bn = blockIdx.x * BN;
  int tr = tid / 16, tc = tid % 16;
  float acc[4][4];
#pragma unroll
  for (int i = 0; i < 4; i++)
#pragma unroll
    for (int j = 0; j < 4; j++) acc[i][j] = 0.f;

  for (int k0 = 0; k0 < K; k0 += BK) {
    for (int i = tid; i < BM * BK; i += 256) {
      int m = i / BK, kk = i % BK;
      As[kk][m] = A[(size_t)(bm + m) * K + k0 + kk];
    }
    for (int i = tid; i < BK * BN; i += 256) {
      int kk = i / BN, n = i % BN;
      Ws[kk][n] = W[(size_t)(k0 + kk) * N + bn + n];
    }
    __syncthreads();
#pragma unroll
    for (int kk = 0; kk < BK; ++kk) {
      float a[4], w[4];
#pragma unroll
      for (int i = 0; i < 4; i++) a[i] = As[kk][tr * 4 + i];
#pragma unroll
      for (int j = 0; j < 4; j++) w[j] = Ws[kk][tc * 4 + j];
#pragma unroll
      for (int i = 0; i < 4; i++)
#pragma unroll
        for (int j = 0; j < 4; j++) acc[i][j] += a[i] * w[j];
    }
    __syncthreads();
  }
#pragma unroll
  for (int i = 0; i < 4; i++) {
    int m = bm + tr * 4 + i;
#pragma unroll
    for (int j = 0; j < 4; j++) {
      int n = bn + tc * 4 + j;
      float v = acc[i][j] + (bias ? bias[n] : 0.f);
      if (MODE == 1) v = gelu_f(v);
      if (MODE == 2) v += res[(size_t)m * N + n];
      C[(size_t)m * N + n] = v;
    }
  }
}

// ---------------- write K/V cache (prefill) ----------------
__global__ void k_write_kv_prefill(const float* __restrict__ qkv, float* __restrict__ kc,
                                   float* __restrict__ vc) {
  int bt = blockIdx.x;
  int b = bt / PROMPT_LEN, t = bt % PROMPT_LEN;
  for (int i = threadIdx.x; i < DIM; i += blockDim.x) {
    int h = i / HEADD, d = i % HEADD;
    size_t ci = ((size_t)(b * NHEAD + h) * TMAX + t) * HEADD + d;
    kc[ci] = qkv[(size_t)bt * 3 * DIM + DIM + i];
    vc[ci] = qkv[(size_t)bt * 3 * DIM + 2 * DIM + i];
  }
}

// ---------------- prefill attention: one block (64 thr) per (b,h,q) ----------------
__global__ void k_attn_prefill(const float* __restrict__ qkv, const float* __restrict__ kc,
                               const float* __restrict__ vc, float* __restrict__ o) {
  int blk = blockIdx.x;
  int q = blk % PROMPT_LEN;
  int bh = blk / PROMPT_LEN;
  int h = bh % NHEAD, b = bh / NHEAD;
  int tid = threadIdx.x;  // 64
  __shared__ float qs[HEADD];
  __shared__ float ps[PROMPT_LEN];
  qs[tid] = qkv[(size_t)(b * PROMPT_LEN + q) * 3 * DIM + h * HEADD + tid];
  __syncthreads();
  const float* kb = kc + (size_t)(b * NHEAD + h) * TMAX * HEADD;
  const float* vb = vc + (size_t)(b * NHEAD + h) * TMAX * HEADD;
  float s = -1e30f;
  if (tid <= q) {
    float a = 0.f;
    for (int d = 0; d < HEADD; ++d) a += qs[d] * kb[tid * HEADD + d];
    s = a * ATT_SCALE;
  }
  float mx = s;
  for (int off = 32; off > 0; off >>= 1) mx = fmaxf(mx, __shfl_xor(mx, off));
  float e = (tid <= q) ? expf(s - mx) : 0.f;
  float sum = e;
  for (int off = 32; off > 0; off >>= 1) sum += __shfl_xor(sum, off);
  ps[tid] = e / sum;
  __syncthreads();
  float acc = 0.f;
  for (int t = 0; t <= q; ++t) acc += ps[t] * vb[t * HEADD + tid];
  o[(size_t)(b * PROMPT_LEN + q) * DIM + h * HEADD + tid] = acc;
}

// ---------------- decode attention: one block (64 thr) per (b,h), appends KV at p ----------------
__global__ void k_attn_decode(const float* __restrict__ qkvd, const int* __restrict__ lens,
                              float* __restrict__ kc, float* __restrict__ vc,
                              float* __restrict__ o) {
  int h = blockIdx.x % NHEAD, b = blockIdx.x / NHEAD;
  int tid = threadIdx.x;  // 64
  int p = lens[b] - 1;
  if (p < 0) p = 0;
  if (p > TMAX - 1) p = TMAX - 1;
  float kself = qkvd[(size_t)b * 3 * DIM + DIM + h * HEADD + tid];
  float vself = qkvd[(size_t)b * 3 * DIM + 2 * DIM + h * HEADD + tid];
  float* kb = kc + (size_t)(b * NHEAD + h) * TMAX * HEADD;
  float* vb = vc + (size_t)(b * NHEAD + h) * TMAX * HEADD;
  kb[p * HEADD + tid] = kself;
  vb[p * HEADD + tid] = vself;
  __shared__ float qs[HEADD];
  __shared__ float ps[TMAX];
  qs[tid] = qkvd[(size_t)b * 3 * DIM + h * HEADD + tid];
  __syncthreads();
  // self dot = sum_d q[d]*k_p[d]
  float pd = qs[tid] * kself;
  for (int off = 32; off > 0; off >>= 1) pd += __shfl_xor(pd, off);
  float selfdot = pd * ATT_SCALE;
  float s0 = -1e30f, s1 = -1e30f;
  int t1 = tid + 64;
  if (tid < p) {
    float a = 0.f;
    for (int d = 0; d < HEADD; ++d) a += qs[d] * kb[tid * HEADD + d];
    s0 = a * ATT_SCALE;
  } else if (tid == p) {
    s0 = selfdot;
  }
  if (t1 < p) {
    float a = 0.f;
    for (int d = 0; d < HEADD; ++d) a += qs[d] * kb[t1 * HEADD + d];
    s1 = a * ATT_SCALE;
  } else if (t1 == p) {
    s1 = selfdot;
  }
  float mx = fmaxf(s0, s1);
  for (int off = 32; off > 0; off >>= 1) mx = fmaxf(mx, __shfl_xor(mx, off));
  float e0 = (tid <= p) ? expf(s0 - mx) : 0.f;
  float e1 = (t1 <= p) ? expf(s1 - mx) : 0.f;
  float sum = e0 + e1;
  for (int off = 32; off > 0; off >>= 1) sum += __shfl_xor(sum, off);
  float inv = 1.f / sum;
  ps[tid] = e0 * inv;
  if (tid < TMAX - 64) ps[t1] = e1 * inv;
  __syncthreads();
  float acc = 0.f;
  for (int t = 0; t < p; ++t) acc += ps[t] * vb[t * HEADD + tid];
  acc += ps[p] * vself;
  o[(size_t)b * DIM + h * HEADD + tid] = acc;
}

// ---------------- skinny GEMM for decode: C[16,N] = A[16,K] @ W[K,N] ----------------
template <int MODE>
__global__ __launch_bounds__(64) void k_gemm_skinny(const float* __restrict__ A,
                                                    const float* __restrict__ W,
                                                    const float* __restrict__ bias,
                                                    const float* __restrict__ res,
                                                    float* __restrict__ C, int N, int K) {
  const int KC = 512;
  __shared__ float As[BATCH][KC];
  int col = blockIdx.x * 64 + threadIdx.x;
  float acc[BATCH];
#pragma unroll
  for (int b = 0; b < BATCH; ++b) acc[b] = 0.f;
  for (int k0 = 0; k0 < K; k0 += KC) {
    for (int i = threadIdx.x; i < BATCH * KC; i += 64) {
      int r = i / KC, c = i % KC;
      As[r][c] = A[(size_t)r * K + k0 + c];
    }
    __syncthreads();
    if (col < N) {
      for (int k = 0; k < KC; ++k) {
        float w = W[(size_t)(k0 + k) * N + col];
#pragma unroll
        for (int b = 0; b < BATCH; ++b) acc[b] += As[b][k] * w;
      }
    }
    __syncthreads();
  }
  if (col < N) {
#pragma unroll
    for (int b = 0; b < BATCH; ++b) {
      float v = acc[b] + (bias ? bias[col] : 0.f);
      if (MODE == 1) v = gelu_f(v);
      if (MODE == 2) v += res[(size_t)b * N + col];
      C[(size_t)b * N + col] = v;
    }
  }
}

// ---------------- per-step state update ----------------
__global__ void k_update(const float* __restrict__ logits, int* __restrict__ ids,
                         int* __restrict__ lens, int* __restrict__ fin, float* __restrict__ csum,
                         float* __restrict__ ccnt, float* __restrict__ out_gen, int step) {
  int b = blockIdx.x, tid = threadIdx.x;
  const float* lr = logits + (size_t)b * VOCAB;
  __shared__ float vred[256];
  __shared__ int ired[256];
  float best = -1e30f;
  int besti = 0;
  for (int i = tid; i < VOCAB; i += 256) {
    float v = lr[i];
    if (v > best) {
      best = v;
      besti = i;
    }
  }
  vred[tid] = best;
  ired[tid] = besti;
  __syncthreads();
  for (int s = 128; s > 0; s >>= 1) {
    if (tid < s) {
      if (vred[tid + s] > vred[tid] ||
          (vred[tid + s] == vred[tid] && ired[tid + s] < ired[tid])) {
        vred[tid] = vred[tid + s];
        ired[tid] = ired[tid + s];
      }
    }
    __syncthreads();
  }
  float mx = vred[0];
  int top = ired[0];
  __syncthreads();
  float se = 0.f;
  for (int i = tid; i < VOCAB; i += 256) se += expf(lr[i] - mx);
  vred[tid] = se;
  __syncthreads();
  for (int s = 128; s > 0; s >>= 1) {
    if (tid < s) vred[tid] += vred[tid + s];
    __syncthreads();
  }
  if (tid == 0) {
    float top_p = 1.f / vred[0];
    int l = lens[b];
    bool active = (!fin[b]) && (l < TMAX);
    if (active) {
      csum[b] += top_p;
      ccnt[b] += 1.f;
    }
    bool is_end = (top == 3) || (top == 0);
    bool wr = active && !is_end;
    if (wr) {
      ids[b * TMAX + l] = top;
      lens[b] = l + 1;
    }
    if (active && is_end) fin[b] = 1;
    out_gen[b * NNEW + step] = wr ? (float)top : 0.f;
  }
}

__global__ void k_finalize(const float* __restrict__ csum, const float* __restrict__ ccnt,
                           float* __restrict__ out) {
  int b = threadIdx.x;
  if (b < BATCH) out[BATCH * NNEW + b] = csum[b] / fmaxf(ccnt[b], 1.f);
}

// ---------------- host launch ----------------
extern "C" void kernel_launch(void* const* d_in, const int* in_sizes, int n_in, void* d_out,
                              int out_size, void* d_ws, size_t ws_size, hipStream_t stream) {
  const float* wte = (const float*)d_in[0];
  const float* wpe = (const float*)d_in[1];
  const float* ln1_w = (const float*)d_in[2];
  const float* ln1_b = (const float*)d_in[3];
  const float* qkv_w = (const float*)d_in[4];
  const float* qkv_b = (const float*)d_in[5];
  const float* ao_w = (const float*)d_in[6];
  const float* ao_b = (const float*)d_in[7];
  const float* ln2_w = (const float*)d_in[8];
  const float* ln2_b = (const float*)d_in[9];
  const float* fc_w = (const float*)d_in[10];
  const float* fc_b = (const float*)d_in[11];
  const float* pr_w = (const float*)d_in[12];
  const float* pr_b = (const float*)d_in[13];
  const float* lnf_w = (const float*)d_in[14];
  const float* lnf_b = (const float*)d_in[15];
  const float* lm_w = (const float*)d_in[16];
  const int* ids_in = (const int*)d_in[17];
  const int* mask_in = (const int*)d_in[18];
  float* out = (float*)d_out;

  char* p = (char*)d_ws;
  auto carve = [&](size_t nbytes) {
    char* r = p;
    p += (nbytes + 255) & ~(size_t)255;
    return (void*)r;
  };
  int* w_ids = (int*)carve(BATCH * TMAX * 4);
  int* w_lens = (int*)carve(BATCH * 4);
  int* w_fin = (int*)carve(BATCH * 4);
  float* w_csum = (float*)carve(BATCH * 4);
  float* w_ccnt = (float*)carve(BATCH * 4);
  float* w_x = (float*)carve((size_t)BATCH * PROMPT_LEN * DIM * 4);
  float* w_h = (float*)carve((size_t)BATCH * PROMPT_LEN * DIM * 4);
  float* w_qkv = (float*)carve((size_t)BATCH * PROMPT_LEN * 3 * DIM * 4);
  float* w_att = (float*)carve((size_t)BATCH * PROMPT_LEN * DIM * 4);
  float* w_mlp = (float*)carve((size_t)BATCH * PROMPT_LEN * 4 * DIM * 4);
  float* w_kc = (float*)carve((size_t)NLAYER * BATCH * NHEAD * TMAX * HEADD * 4);
  float* w_vc = (float*)carve((size_t)NLAYER * BATCH * NHEAD * TMAX * HEADD * 4);
  float* w_xd = (float*)carve(BATCH * DIM * 4);
  float* w_hd = (float*)carve(BATCH * DIM * 4);
  float* w_qkvd = (float*)carve(BATCH * 3 * DIM * 4);
  float* w_od = (float*)carve(BATCH * DIM * 4);
  float* w_mlpd = (float*)carve(BATCH * 4 * DIM * 4);
  float* w_logits = (float*)carve((size_t)BATCH * VOCAB * 4);

  const int M = BATCH * PROMPT_LEN;  // 1024
  const size_t kvstride = (size_t)BATCH * NHEAD * TMAX * HEADD;

  k_init<<<1, 256, 0, stream>>>(ids_in, mask_in, w_ids, w_lens, w_fin, w_csum, w_ccnt);
  k_embed_prefill<<<M, 256, 0, stream>>>(w_ids, wte, wpe, w_x);

  for (int l = 0; l < NLAYER; ++l) {
    float* kc = w_kc + (size_t)l * kvstride;
    float* vc = w_vc + (size_t)l * kvstride;
    k_layernorm<<<M, 256, 0, stream>>>(w_x, ln1_w + l * DIM, ln1_b + l * DIM, w_h);
    gemm_kernel<0><<<dim3(3 * DIM / 64, M / 64), 256, 0, stream>>>(
        w_h, qkv_w + (size_t)l * DIM * 3 * DIM, qkv_b + (size_t)l * 3 * DIM, nullptr, w_qkv, M,
        3 * DIM, DIM);
    k_write_kv_prefill<<<M, 128, 0, stream>>>(w_qkv, kc, vc);
    k_attn_prefill<<<BATCH * NHEAD * PROMPT_LEN, 64, 0, stream>>>(w_qkv, kc, vc, w_att);
    gemm_kernel<2><<<dim3(DIM / 64, M / 64), 256, 0, stream>>>(
        w_att, ao_w + (size_t)l * DIM * DIM, ao_b + (size_t)l * DIM, w_x, w_x, M, DIM, DIM);
    k_layernorm<<<M, 256, 0, stream>>>(w_x, ln2_w + l * DIM, ln2_b + l * DIM, w_h);
    gemm_kernel<1><<<dim3(4 * DIM / 64, M / 64), 256, 0, stream>>>(
        w_h, fc_w + (size_t)l * DIM * 4 * DIM, fc_b + (size_t)l * 4 * DIM, nullptr, w_mlp, M,
        4 * DIM, DIM);
    gemm_kernel<2><<<dim3(DIM / 64, M / 64), 256, 0, stream>>>(
        w_mlp, pr_w + (size_t)l * 4 * DIM * DIM, pr_b + (size_t)l * DIM, w_x, w_x, M, DIM,
        4 * DIM);
  }

  for (int s = 0; s < NNEW; ++s) {
    k_embed_decode<<<BATCH, 256, 0, stream>>>(w_ids, w_lens, wte, wpe, w_xd);
    for (int l = 0; l < NLAYER; ++l) {
      float* kc = w_kc + (size_t)l * kvstride;
      float* vc = w_vc + (size_t)l * kvstride;
      k_layernorm<<<BATCH, 256, 0, stream>>>(w_xd, ln1_w + l * DIM, ln1_b + l * DIM, w_hd);
      k_gemm_skinny<0><<<(3 * DIM) / 64, 64, 0, stream>>>(
          w_hd, qkv_w + (size_t)l * DIM * 3 * DIM, qkv_b + (size_t)l * 3 * DIM, nullptr, w_qkvd,
          3 * DIM, DIM);
      k_attn_decode<<<BATCH * NHEAD, 64, 0, stream>>>(w_qkvd, w_lens, kc, vc, w_od);
      k_gemm_skinny<2><<<DIM / 64, 64, 0, stream>>>(w_od, ao_w + (size_t)l * DIM * DIM,
                                                    ao_b + (size_t)l * DIM, w_xd, w_xd, DIM, DIM);
      k_layernorm<<<BATCH, 256, 0, stream>>>(w_xd, ln2_w + l * DIM, ln2_b + l * DIM, w_hd);
      k_gemm_skinny<1><<<(4 * DIM) / 64, 64, 0, stream>>>(
          w_hd, fc_w + (size_t)l * DIM * 4 * DIM, fc_b + (size_t)l * 4 * DIM, nullptr, w_mlpd,
          4 * DIM, DIM);
      k_gemm_skinny<2><<<DIM / 64, 64, 0, stream>>>(w_mlpd, pr_w + (size_t)l * 4 * DIM * DIM,
                                                    pr_b + (size_t)l * DIM, w_xd, w_xd, DIM,
                                                    4 * DIM);
    }
    k_layernorm<<<BATCH, 256, 0, stream>>>(w_xd, lnf_w, lnf_b, w_hd);
    k_gemm_skinny<0><<<(VOCAB + 63) / 64, 64, 0, stream>>>(w_hd, lm_w, nullptr, nullptr, w_logits,
                                                           VOCAB, DIM);
    k_update<<<BATCH, 256, 0, stream>>>(w_logits, w_ids, w_lens, w_fin, w_csum, w_ccnt, out, s);
  }
  k_finalize<<<1, 64, 0, stream>>>(w_csum, w_ccnt, out);
}

// Round 2
// 34990.512 us; speedup vs baseline: 2.4896x; 2.4896x over previous
//
#include <hip/hip_runtime.h>
#include <math.h>

#define VOCAB 8000
#define DIM 512
#define NLAYER 8
#define NHEAD 8
#define BATCH 16
#define TMAX 80
#define PROMPT_LEN 64
#define NNEW 16
#define HEADD 64
#define ATT_SCALE 0.125f

__device__ __forceinline__ float gelu_f(float x) {
  return 0.5f * x * (1.0f + tanhf(0.7978845608028654f * (x + 0.044715f * x * x * x)));
}

// ---------------- init ----------------
__global__ void k_init(const int* __restrict__ ids_in, const int* __restrict__ mask_in,
                       int* __restrict__ ids, int* __restrict__ lens, int* __restrict__ fin,
                       float* __restrict__ csum, float* __restrict__ ccnt) {
  int tid = threadIdx.x;
  for (int i = tid; i < BATCH * TMAX; i += blockDim.x) ids[i] = ids_in[i];
  if (tid < BATCH) {
    int s = 0;
    for (int t = 0; t < TMAX; ++t) s += mask_in[tid * TMAX + t];
    lens[tid] = s;
    fin[tid] = 0;
    csum[tid] = 0.f;
    ccnt[tid] = 0.f;
  }
}

// ---------------- embedding ----------------
__global__ void k_embed_prefill(const int* __restrict__ ids, const float* __restrict__ wte,
                                const float* __restrict__ wpe, float* __restrict__ x) {
  int bt = blockIdx.x;
  int b = bt / PROMPT_LEN, t = bt % PROMPT_LEN;
  int tok = ids[b * TMAX + t];
  for (int d = threadIdx.x; d < DIM; d += blockDim.x)
    x[(size_t)bt * DIM + d] = wte[(size_t)tok * DIM + d] + wpe[(size_t)t * DIM + d];
}

__global__ void k_embed_decode(const int* __restrict__ ids, const int* __restrict__ lens,
                               const float* __restrict__ wte, const float* __restrict__ wpe,
                               float* __restrict__ xd) {
  int b = blockIdx.x;
  int p = lens[b] - 1;
  if (p < 0) p = 0;
  if (p > TMAX - 1) p = TMAX - 1;
  int tok = ids[b * TMAX + p];
  for (int d = threadIdx.x; d < DIM; d += blockDim.x)
    xd[(size_t)b * DIM + d] = wte[(size_t)tok * DIM + d] + wpe[(size_t)p * DIM + d];
}

// ---------------- layernorm (prefill; one block of 256 per row of 512) ----------------
__global__ void k_layernorm(const float* __restrict__ x, const float* __restrict__ w,
                            const float* __restrict__ b, float* __restrict__ out) {
  int row = blockIdx.x;
  int tid = threadIdx.x;
  const float* xr = x + (size_t)row * DIM;
  __shared__ float red[256];
  float v0 = xr[tid], v1 = xr[tid + 256];
  red[tid] = v0 + v1;
  __syncthreads();
  for (int s = 128; s > 0; s >>= 1) {
    if (tid < s) red[tid] += red[tid + s];
    __syncthreads();
  }
  float mean = red[0] * (1.0f / DIM);
  __syncthreads();
  float d0 = v0 - mean, d1 = v1 - mean;
  red[tid] = d0 * d0 + d1 * d1;
  __syncthreads();
  for (int s = 128; s > 0; s >>= 1) {
    if (tid < s) red[tid] += red[tid + s];
    __syncthreads();
  }
  float rstd = 1.0f / sqrtf(red[0] * (1.0f / DIM) + 1e-5f);
  out[(size_t)row * DIM + tid] = d0 * rstd * w[tid] + b[tid];
  out[(size_t)row * DIM + tid + 256] = d1 * rstd * w[tid + 256] + b[tid + 256];
}

// ---------------- layernorm with TRANSPOSED output At[512][16] (decode) ----------------
__global__ void k_ln_t(const float* __restrict__ x, const float* __restrict__ w,
                       const float* __restrict__ b, float* __restrict__ At) {
  int row = blockIdx.x;  // 16 rows
  int tid = threadIdx.x; // 256
  const float* xr = x + (size_t)row * DIM;
  __shared__ float red[256];
  float v0 = xr[tid], v1 = xr[tid + 256];
  red[tid] = v0 + v1;
  __syncthreads();
  for (int s = 128; s > 0; s >>= 1) {
    if (tid < s) red[tid] += red[tid + s];
    __syncthreads();
  }
  float mean = red[0] * (1.0f / DIM);
  __syncthreads();
  float d0 = v0 - mean, d1 = v1 - mean;
  red[tid] = d0 * d0 + d1 * d1;
  __syncthreads();
  for (int s = 128; s > 0; s >>= 1) {
    if (tid < s) red[tid] += red[tid + s];
    __syncthreads();
  }
  float rstd = 1.0f / sqrtf(red[0] * (1.0f / DIM) + 1e-5f);
  At[(size_t)tid * BATCH + row] = d0 * rstd * w[tid] + b[tid];
  At[(size_t)(tid + 256) * BATCH + row] = d1 * rstd * w[tid + 256] + b[tid + 256];
}

// ---------------- tiled fp32 GEMM (prefill): C[M,N] = A[M,K] @ W[K,N] ----------------
// MODE: 0 = +bias, 1 = gelu(+bias), 2 = +bias +res
template <int MODE>
__global__ __launch_bounds__(256) void gemm_kernel(const float* __restrict__ A,
                                                   const float* __restrict__ W,
                                                   const float* __restrict__ bias,
                                                   const float* __restrict__ res,
                                                   float* __restrict__ C, int M, int N, int K) {
  const int BM = 64, BN = 64, BK = 16;
  __shared__ float As[BK][BM + 1];
  __shared__ float Ws[BK][BN];
  int tid = threadIdx.x;
  int bm = blockIdx.y * BM, bn = blockIdx.x * BN;
  int tr = tid / 16, tc = tid % 16;
  float acc[4][4];
#pragma unroll
  for (int i = 0; i < 4; i++)
#pragma unroll
    for (int j = 0; j < 4; j++) acc[i][j] = 0.f;

  for (int k0 = 0; k0 < K; k0 += BK) {
    for (int i = tid; i < BM * BK; i += 256) {
      int m = i / BK, kk = i % BK;
      As[kk][m] = A[(size_t)(bm + m) * K + k0 + kk];
    }
    for (int i = tid; i < BK * BN; i += 256) {
      int kk = i / BN, n = i % BN;
      Ws[kk][n] = W[(size_t)(k0 + kk) * N + bn + n];
    }
    __syncthreads();
#pragma unroll
    for (int kk = 0; kk < BK; ++kk) {
      float a[4], w[4];
#pragma unroll
      for (int i = 0; i < 4; i++) a[i] = As[kk][tr * 4 + i];
#pragma unroll
      for (int j = 0; j < 4; j++) w[j] = Ws[kk][tc * 4 + j];
#pragma unroll
      for (int i = 0; i < 4; i++)
#pragma unroll
        for (int j = 0; j < 4; j++) acc[i][j] += a[i] * w[j];
    }
    __syncthreads();
  }
#pragma unroll
  for (int i = 0; i < 4; i++) {
    int m = bm + tr * 4 + i;
#pragma unroll
    for (int j = 0; j < 4; j++) {
      int n = bn + tc * 4 + j;
      float v = acc[i][j] + (bias ? bias[n] : 0.f);
      if (MODE == 1) v = gelu_f(v);
      if (MODE == 2) v += res[(size_t)m * N + n];
      C[(size_t)m * N + n] = v;
    }
  }
}

// ---------------- write K/V cache (prefill) ----------------
__global__ void k_write_kv_prefill(const float* __restrict__ qkv, float* __restrict__ kc,
                                   float* __restrict__ vc) {
  int bt = blockIdx.x;
  int b = bt / PROMPT_LEN, t = bt % PROMPT_LEN;
  for (int i = threadIdx.x; i < DIM; i += blockDim.x) {
    int h = i / HEADD, d = i % HEADD;
    size_t ci = ((size_t)(b * NHEAD + h) * TMAX + t) * HEADD + d;
    kc[ci] = qkv[(size_t)bt * 3 * DIM + DIM + i];
    vc[ci] = qkv[(size_t)bt * 3 * DIM + 2 * DIM + i];
  }
}

// ---------------- prefill attention: one block (64 thr) per (b,h,q) ----------------
__global__ void k_attn_prefill(const float* __restrict__ qkv, const float* __restrict__ kc,
                               const float* __restrict__ vc, float* __restrict__ o) {
  int blk = blockIdx.x;
  int q = blk % PROMPT_LEN;
  int bh = blk / PROMPT_LEN;
  int h = bh % NHEAD, b = bh / NHEAD;
  int tid = threadIdx.x;  // 64
  __shared__ float qs[HEADD];
  __shared__ float ps[PROMPT_LEN];
  qs[tid] = qkv[(size_t)(b * PROMPT_LEN + q) * 3 * DIM + h * HEADD + tid];
  __syncthreads();
  const float* kb = kc + (size_t)(b * NHEAD + h) * TMAX * HEADD;
  const float* vb = vc + (size_t)(b * NHEAD + h) * TMAX * HEADD;
  float s = -1e30f;
  if (tid <= q) {
    float a = 0.f;
    for (int d = 0; d < HEADD; ++d) a += qs[d] * kb[tid * HEADD + d];
    s = a * ATT_SCALE;
  }
  float mx = s;
  for (int off = 32; off > 0; off >>= 1) mx = fmaxf(mx, __shfl_xor(mx, off));
  float e = (tid <= q) ? expf(s - mx) : 0.f;
  float sum = e;
  for (int off = 32; off > 0; off >>= 1) sum += __shfl_xor(sum, off);
  ps[tid] = e / sum;
  __syncthreads();
  float acc = 0.f;
  for (int t = 0; t <= q; ++t) acc += ps[t] * vb[t * HEADD + tid];
  o[(size_t)(b * PROMPT_LEN + q) * DIM + h * HEADD + tid] = acc;
}

// ---------------- decode attention: one block (64 thr) per (b,h), appends KV at p ----------------
// Writes TRANSPOSED output Ot[512][16] for the following skinny GEMM.
__global__ void k_attn_decode(const float* __restrict__ qkvd, const int* __restrict__ lens,
                              float* __restrict__ kc, float* __restrict__ vc,
                              float* __restrict__ ot) {
  int h = blockIdx.x % NHEAD, b = blockIdx.x / NHEAD;
  int tid = threadIdx.x;  // 64
  int p = lens[b] - 1;
  if (p < 0) p = 0;
  if (p > TMAX - 1) p = TMAX - 1;
  float kself = qkvd[(size_t)b * 3 * DIM + DIM + h * HEADD + tid];
  float vself = qkvd[(size_t)b * 3 * DIM + 2 * DIM + h * HEADD + tid];
  float* kb = kc + (size_t)(b * NHEAD + h) * TMAX * HEADD;
  float* vb = vc + (size_t)(b * NHEAD + h) * TMAX * HEADD;
  kb[p * HEADD + tid] = kself;
  vb[p * HEADD + tid] = vself;
  __shared__ float qs[HEADD];
  __shared__ float ps[TMAX];
  qs[tid] = qkvd[(size_t)b * 3 * DIM + h * HEADD + tid];
  __syncthreads();
  float pd = qs[tid] * kself;
  for (int off = 32; off > 0; off >>= 1) pd += __shfl_xor(pd, off);
  float selfdot = pd * ATT_SCALE;
  float s0 = -1e30f, s1 = -1e30f;
  int t1 = tid + 64;
  if (tid < p) {
    float a = 0.f;
    for (int d = 0; d < HEADD; ++d) a += qs[d] * kb[tid * HEADD + d];
    s0 = a * ATT_SCALE;
  } else if (tid == p) {
    s0 = selfdot;
  }
  if (t1 < p) {
    float a = 0.f;
    for (int d = 0; d < HEADD; ++d) a += qs[d] * kb[t1 * HEADD + d];
    s1 = a * ATT_SCALE;
  } else if (t1 == p) {
    s1 = selfdot;
  }
  float mx = fmaxf(s0, s1);
  for (int off = 32; off > 0; off >>= 1) mx = fmaxf(mx, __shfl_xor(mx, off));
  float e0 = (tid <= p) ? expf(s0 - mx) : 0.f;
  float e1 = (t1 <= p) ? expf(s1 - mx) : 0.f;
  float sum = e0 + e1;
  for (int off = 32; off > 0; off >>= 1) sum += __shfl_xor(sum, off);
  float inv = 1.f / sum;
  ps[tid] = e0 * inv;
  if (tid < TMAX - 64) ps[t1] = e1 * inv;
  __syncthreads();
  float acc = 0.f;
  for (int t = 0; t < p; ++t) acc += ps[t] * vb[t * HEADD + tid];
  acc += ps[p] * vself;
  ot[(size_t)(h * HEADD + tid) * BATCH + b] = acc;
}

// ---------------- decode skinny GEMM: C[16,N] = At^T[16,K] @ W[K,N] ----------------
// At is [K][16] (transposed activations) -> wave-uniform scalar loads, no LDS in K-loop.
// In-block split-K across WAVES waves + deterministic LDS reduce + fused epilogue.
// MODE: 0 = +bias (write C row-major), 1 = gelu(+bias) -> write Ct TRANSPOSED only,
//       2 = +bias + residual into C (read-modify-write), 3 = plain (no bias), write C.
template <int WAVES, int MODE>
__global__ __launch_bounds__(WAVES * 64) void k_skinny(const float* __restrict__ At,
                                                       const float* __restrict__ W,
                                                       const float* __restrict__ bias,
                                                       float* __restrict__ C,
                                                       float* __restrict__ Ct, int N, int K) {
  const int lane = threadIdx.x & 63;
  const int w = threadIdx.x >> 6;
  const int col = blockIdx.x * 64 + lane;
  const int kchunk = K / WAVES;
  const int k0 = w * kchunk;
  float acc[BATCH];
#pragma unroll
  for (int b = 0; b < BATCH; ++b) acc[b] = 0.f;
  const float* Wp = W + (size_t)k0 * N + col;
  const float* Ap = At + (size_t)k0 * BATCH;
  for (int k = 0; k < kchunk; k += 4) {
#pragma unroll
    for (int u = 0; u < 4; ++u) {
      float wv = Wp[(size_t)(k + u) * N];
      const float4* a4 = (const float4*)(Ap + (size_t)(k + u) * BATCH);
      float4 A0 = a4[0], A1 = a4[1], A2 = a4[2], A3 = a4[3];
      acc[0] = fmaf(A0.x, wv, acc[0]);
      acc[1] = fmaf(A0.y, wv, acc[1]);
      acc[2] = fmaf(A0.z, wv, acc[2]);
      acc[3] = fmaf(A0.w, wv, acc[3]);
      acc[4] = fmaf(A1.x, wv, acc[4]);
      acc[5] = fmaf(A1.y, wv, acc[5]);
      acc[6] = fmaf(A1.z, wv, acc[6]);
      acc[7] = fmaf(A1.w, wv, acc[7]);
      acc[8] = fmaf(A2.x, wv, acc[8]);
      acc[9] = fmaf(A2.y, wv, acc[9]);
      acc[10] = fmaf(A2.z, wv, acc[10]);
      acc[11] = fmaf(A2.w, wv, acc[11]);
      acc[12] = fmaf(A3.x, wv, acc[12]);
      acc[13] = fmaf(A3.y, wv, acc[13]);
      acc[14] = fmaf(A3.z, wv, acc[14]);
      acc[15] = fmaf(A3.w, wv, acc[15]);
    }
  }
  __shared__ float red[WAVES][BATCH][64];
#pragma unroll
  for (int b = 0; b < BATCH; ++b) red[w][b][lane] = acc[b];
  __syncthreads();
  const int TOT = WAVES * 64;
  for (int o = threadIdx.x; o < BATCH * 64; o += TOT) {
    int b = o >> 6, n = o & 63;
    float v = 0.f;
#pragma unroll
    for (int ww = 0; ww < WAVES; ++ww) v += red[ww][b][n];
    int gn = blockIdx.x * 64 + n;
    if (MODE != 3) v += bias[gn];
    if (MODE == 1) {
      v = gelu_f(v);
      Ct[(size_t)gn * BATCH + b] = v;
    } else {
      if (MODE == 2) v += C[(size_t)b * N + gn];
      C[(size_t)b * N + gn] = v;
    }
  }
}

// ---------------- per-step state update ----------------
__global__ void k_update(const float* __restrict__ logits, int* __restrict__ ids,
                         int* __restrict__ lens, int* __restrict__ fin, float* __restrict__ csum,
                         float* __restrict__ ccnt, float* __restrict__ out_gen, int step) {
  int b = blockIdx.x, tid = threadIdx.x;
  const float* lr = logits + (size_t)b * VOCAB;
  __shared__ float vred[256];
  __shared__ int ired[256];
  float best = -1e30f;
  int besti = 0;
  for (int i = tid; i < VOCAB; i += 256) {
    float v = lr[i];
    if (v > best) {
      best = v;
      besti = i;
    }
  }
  vred[tid] = best;
  ired[tid] = besti;
  __syncthreads();
  for (int s = 128; s > 0; s >>= 1) {
    if (tid < s) {
      if (vred[tid + s] > vred[tid] ||
          (vred[tid + s] == vred[tid] && ired[tid + s] < ired[tid])) {
        vred[tid] = vred[tid + s];
        ired[tid] = ired[tid + s];
      }
    }
    __syncthreads();
  }
  float mx = vred[0];
  int top = ired[0];
  __syncthreads();
  float se = 0.f;
  for (int i = tid; i < VOCAB; i += 256) se += expf(lr[i] - mx);
  vred[tid] = se;
  __syncthreads();
  for (int s = 128; s > 0; s >>= 1) {
    if (tid < s) vred[tid] += vred[tid + s];
    __syncthreads();
  }
  if (tid == 0) {
    float top_p = 1.f / vred[0];
    int l = lens[b];
    bool active = (!fin[b]) && (l < TMAX);
    if (active) {
      csum[b] += top_p;
      ccnt[b] += 1.f;
    }
    bool is_end = (top == 3) || (top == 0);
    bool wr = active && !is_end;
    if (wr) {
      ids[b * TMAX + l] = top;
      lens[b] = l + 1;
    }
    if (active && is_end) fin[b] = 1;
    out_gen[b * NNEW + step] = wr ? (float)top : 0.f;
  }
}

__global__ void k_finalize(const float* __restrict__ csum, const float* __restrict__ ccnt,
                           float* __restrict__ out) {
  int b = threadIdx.x;
  if (b < BATCH) out[BATCH * NNEW + b] = csum[b] / fmaxf(ccnt[b], 1.f);
}

// ---------------- host launch ----------------
extern "C" void kernel_launch(void* const* d_in, const int* in_sizes, int n_in, void* d_out,
                              int out_size, void* d_ws, size_t ws_size, hipStream_t stream) {
  const float* wte = (const float*)d_in[0];
  const float* wpe = (const float*)d_in[1];
  const float* ln1_w = (const float*)d_in[2];
  const float* ln1_b = (const float*)d_in[3];
  const float* qkv_w = (const float*)d_in[4];
  const float* qkv_b = (const float*)d_in[5];
  const float* ao_w = (const float*)d_in[6];
  const float* ao_b = (const float*)d_in[7];
  const float* ln2_w = (const float*)d_in[8];
  const float* ln2_b = (const float*)d_in[9];
  const float* fc_w = (const float*)d_in[10];
  const float* fc_b = (const float*)d_in[11];
  const float* pr_w = (const float*)d_in[12];
  const float* pr_b = (const float*)d_in[13];
  const float* lnf_w = (const float*)d_in[14];
  const float* lnf_b = (const float*)d_in[15];
  const float* lm_w = (const float*)d_in[16];
  const int* ids_in = (const int*)d_in[17];
  const int* mask_in = (const int*)d_in[18];
  float* out = (float*)d_out;

  char* p = (char*)d_ws;
  auto carve = [&](size_t nbytes) {
    char* r = p;
    p += (nbytes + 255) & ~(size_t)255;
    return (void*)r;
  };
  int* w_ids = (int*)carve(BATCH * TMAX * 4);
  int* w_lens = (int*)carve(BATCH * 4);
  int* w_fin = (int*)carve(BATCH * 4);
  float* w_csum = (float*)carve(BATCH * 4);
  float* w_ccnt = (float*)carve(BATCH * 4);
  float* w_x = (float*)carve((size_t)BATCH * PROMPT_LEN * DIM * 4);
  float* w_h = (float*)carve((size_t)BATCH * PROMPT_LEN * DIM * 4);
  float* w_qkv = (float*)carve((size_t)BATCH * PROMPT_LEN * 3 * DIM * 4);
  float* w_att = (float*)carve((size_t)BATCH * PROMPT_LEN * DIM * 4);
  float* w_mlp = (float*)carve((size_t)BATCH * PROMPT_LEN * 4 * DIM * 4);
  float* w_kc = (float*)carve((size_t)NLAYER * BATCH * NHEAD * TMAX * HEADD * 4);
  float* w_vc = (float*)carve((size_t)NLAYER * BATCH * NHEAD * TMAX * HEADD * 4);
  float* w_xd = (float*)carve(BATCH * DIM * 4);
  float* w_at = (float*)carve((size_t)DIM * BATCH * 4);        // At[512][16]
  float* w_qkvd = (float*)carve(BATCH * 3 * DIM * 4);
  float* w_ot = (float*)carve((size_t)DIM * BATCH * 4);        // Ot[512][16]
  float* w_gt = (float*)carve((size_t)4 * DIM * BATCH * 4);    // Gt[2048][16]
  float* w_logits = (float*)carve((size_t)BATCH * VOCAB * 4);

  const int M = BATCH * PROMPT_LEN;  // 1024
  const size_t kvstride = (size_t)BATCH * NHEAD * TMAX * HEADD;

  k_init<<<1, 256, 0, stream>>>(ids_in, mask_in, w_ids, w_lens, w_fin, w_csum, w_ccnt);
  k_embed_prefill<<<M, 256, 0, stream>>>(w_ids, wte, wpe, w_x);

  for (int l = 0; l < NLAYER; ++l) {
    float* kc = w_kc + (size_t)l * kvstride;
    float* vc = w_vc + (size_t)l * kvstride;
    k_layernorm<<<M, 256, 0, stream>>>(w_x, ln1_w + l * DIM, ln1_b + l * DIM, w_h);
    gemm_kernel<0><<<dim3(3 * DIM / 64, M / 64), 256, 0, stream>>>(
        w_h, qkv_w + (size_t)l * DIM * 3 * DIM, qkv_b + (size_t)l * 3 * DIM, nullptr, w_qkv, M,
        3 * DIM, DIM);
    k_write_kv_prefill<<<M, 128, 0, stream>>>(w_qkv, kc, vc);
    k_attn_prefill<<<BATCH * NHEAD * PROMPT_LEN, 64, 0, stream>>>(w_qkv, kc, vc, w_att);
    gemm_kernel<2><<<dim3(DIM / 64, M / 64), 256, 0, stream>>>(
        w_att, ao_w + (size_t)l * DIM * DIM, ao_b + (size_t)l * DIM, w_x, w_x, M, DIM, DIM);
    k_layernorm<<<M, 256, 0, stream>>>(w_x, ln2_w + l * DIM, ln2_b + l * DIM, w_h);
    gemm_kernel<1><<<dim3(4 * DIM / 64, M / 64), 256, 0, stream>>>(
        w_h, fc_w + (size_t)l * DIM * 4 * DIM, fc_b + (size_t)l * 4 * DIM, nullptr, w_mlp, M,
        4 * DIM, DIM);
    gemm_kernel<2><<<dim3(DIM / 64, M / 64), 256, 0, stream>>>(
        w_mlp, pr_w + (size_t)l * 4 * DIM * DIM, pr_b + (size_t)l * DIM, w_x, w_x, M, DIM,
        4 * DIM);
  }

  for (int s = 0; s < NNEW; ++s) {
    k_embed_decode<<<BATCH, 256, 0, stream>>>(w_ids, w_lens, wte, wpe, w_xd);
    for (int l = 0; l < NLAYER; ++l) {
      float* kc = w_kc + (size_t)l * kvstride;
      float* vc = w_vc + (size_t)l * kvstride;
      // LN1 -> At (transposed)
      k_ln_t<<<BATCH, 256, 0, stream>>>(w_xd, ln1_w + l * DIM, ln1_b + l * DIM, w_at);
      // QKV: [16,1536] = At^T @ qkv_w
      k_skinny<4, 0><<<3 * DIM / 64, 256, 0, stream>>>(
          w_at, qkv_w + (size_t)l * DIM * 3 * DIM, qkv_b + (size_t)l * 3 * DIM, w_qkvd, nullptr,
          3 * DIM, DIM);
      // attention (writes Ot transposed)
      k_attn_decode<<<BATCH * NHEAD, 64, 0, stream>>>(w_qkvd, w_lens, kc, vc, w_ot);
      // AO: x_d += Ot^T @ ao_w + ao_b
      k_skinny<4, 2><<<DIM / 64, 256, 0, stream>>>(w_ot, ao_w + (size_t)l * DIM * DIM,
                                                   ao_b + (size_t)l * DIM, w_xd, nullptr, DIM,
                                                   DIM);
      // LN2 -> At
      k_ln_t<<<BATCH, 256, 0, stream>>>(w_xd, ln2_w + l * DIM, ln2_b + l * DIM, w_at);
      // FC: Gt[2048][16] = gelu(At^T @ fc_w + fc_b) transposed
      k_skinny<4, 1><<<4 * DIM / 64, 256, 0, stream>>>(
          w_at, fc_w + (size_t)l * DIM * 4 * DIM, fc_b + (size_t)l * 4 * DIM, nullptr, w_gt,
          4 * DIM, DIM);
      // PR: x_d += Gt^T @ pr_w + pr_b   (K=2048 -> 8-wave split)
      k_skinny<8, 2><<<DIM / 64, 512, 0, stream>>>(w_gt, pr_w + (size_t)l * 4 * DIM * DIM,
                                                   pr_b + (size_t)l * DIM, w_xd, nullptr, DIM,
                                                   4 * DIM);
    }
    // final LN -> At, logits = At^T @ lm_w
    k_ln_t<<<BATCH, 256, 0, stream>>>(w_xd, lnf_w, lnf_b, w_at);
    k_skinny<4, 3><<<VOCAB / 64, 256, 0, stream>>>(w_at, lm_w, nullptr, w_logits, nullptr, VOCAB,
                                                   DIM);
    k_update<<<BATCH, 256, 0, stream>>>(w_logits, w_ids, w_lens, w_fin, w_csum, w_ccnt, out, s);
  }
  k_finalize<<<1, 64, 0, stream>>>(w_csum, w_ccnt, out);
}

// Round 3
// 13718.498 us; speedup vs baseline: 6.3499x; 2.5506x over previous
//
#include <hip/hip_runtime.h>
#include <math.h>

#define VOCAB 8000
#define DIM 512
#define NLAYER 8
#define NHEAD 8
#define BATCH 16
#define TMAX 80
#define PROMPT_LEN 64
#define NNEW 16
#define HEADD 64
#define ATT_SCALE 0.125f

__device__ __forceinline__ float gelu_f(float x) {
  return 0.5f * x * (1.0f + tanhf(0.7978845608028654f * (x + 0.044715f * x * x * x)));
}

// ---------------- init ----------------
__global__ void k_init(const int* __restrict__ ids_in, const int* __restrict__ mask_in,
                       int* __restrict__ ids, int* __restrict__ lens, int* __restrict__ fin,
                       float* __restrict__ csum, float* __restrict__ ccnt) {
  int tid = threadIdx.x;
  for (int i = tid; i < BATCH * TMAX; i += blockDim.x) ids[i] = ids_in[i];
  if (tid < BATCH) {
    int s = 0;
    for (int t = 0; t < TMAX; ++t) s += mask_in[tid * TMAX + t];
    lens[tid] = s;
    fin[tid] = 0;
    csum[tid] = 0.f;
    ccnt[tid] = 0.f;
  }
}

// ---------------- prefill embedding ----------------
__global__ void k_embed_prefill(const int* __restrict__ ids, const float* __restrict__ wte,
                                const float* __restrict__ wpe, float* __restrict__ x) {
  int bt = blockIdx.x;
  int b = bt / PROMPT_LEN, t = bt % PROMPT_LEN;
  int tok = ids[b * TMAX + t];
  for (int d = threadIdx.x; d < DIM; d += blockDim.x)
    x[(size_t)bt * DIM + d] = wte[(size_t)tok * DIM + d] + wpe[(size_t)t * DIM + d];
}

// ---------------- prefill layernorm ----------------
__global__ void k_layernorm(const float* __restrict__ x, const float* __restrict__ w,
                            const float* __restrict__ b, float* __restrict__ out) {
  int row = blockIdx.x;
  int tid = threadIdx.x;
  const float* xr = x + (size_t)row * DIM;
  __shared__ float red[256];
  float v0 = xr[tid], v1 = xr[tid + 256];
  red[tid] = v0 + v1;
  __syncthreads();
  for (int s = 128; s > 0; s >>= 1) {
    if (tid < s) red[tid] += red[tid + s];
    __syncthreads();
  }
  float mean = red[0] * (1.0f / DIM);
  __syncthreads();
  float d0 = v0 - mean, d1 = v1 - mean;
  red[tid] = d0 * d0 + d1 * d1;
  __syncthreads();
  for (int s = 128; s > 0; s >>= 1) {
    if (tid < s) red[tid] += red[tid + s];
    __syncthreads();
  }
  float rstd = 1.0f / sqrtf(red[0] * (1.0f / DIM) + 1e-5f);
  out[(size_t)row * DIM + tid] = d0 * rstd * w[tid] + b[tid];
  out[(size_t)row * DIM + tid + 256] = d1 * rstd * w[tid + 256] + b[tid + 256];
}

// ---------------- prefill tiled GEMM ----------------
template <int MODE>
__global__ __launch_bounds__(256) void gemm_kernel(const float* __restrict__ A,
                                                   const float* __restrict__ W,
                                                   const float* __restrict__ bias,
                                                   const float* __restrict__ res,
                                                   float* __restrict__ C, int M, int N, int K) {
  const int BM = 64, BN = 64, BK = 16;
  __shared__ float As[BK][BM + 1];
  __shared__ float Ws[BK][BN];
  int tid = threadIdx.x;
  int bm = blockIdx.y * BM, bn = blockIdx.x * BN;
  int tr = tid / 16, tc = tid % 16;
  float acc[4][4];
#pragma unroll
  for (int i = 0; i < 4; i++)
#pragma unroll
    for (int j = 0; j < 4; j++) acc[i][j] = 0.f;

  for (int k0 = 0; k0 < K; k0 += BK) {
    for (int i = tid; i < BM * BK; i += 256) {
      int m = i / BK, kk = i % BK;
      As[kk][m] = A[(size_t)(bm + m) * K + k0 + kk];
    }
    for (int i = tid; i < BK * BN; i += 256) {
      int kk = i / BN, n = i % BN;
      Ws[kk][n] = W[(size_t)(k0 + kk) * N + bn + n];
    }
    __syncthreads();
#pragma unroll
    for (int kk = 0; kk < BK; ++kk) {
      float a[4], w[4];
#pragma unroll
      for (int i = 0; i < 4; i++) a[i] = As[kk][tr * 4 + i];
#pragma unroll
      for (int j = 0; j < 4; j++) w[j] = Ws[kk][tc * 4 + j];
#pragma unroll
      for (int i = 0; i < 4; i++)
#pragma unroll
        for (int j = 0; j < 4; j++) acc[i][j] += a[i] * w[j];
    }
    __syncthreads();
  }
#pragma unroll
  for (int i = 0; i < 4; i++) {
    int m = bm + tr * 4 + i;
#pragma unroll
    for (int j = 0; j < 4; j++) {
      int n = bn + tc * 4 + j;
      float v = acc[i][j] + (bias ? bias[n] : 0.f);
      if (MODE == 1) v = gelu_f(v);
      if (MODE == 2) v += res[(size_t)m * N + n];
      C[(size_t)m * N + n] = v;
    }
  }
}

// ---------------- write K/V cache (prefill) ----------------
__global__ void k_write_kv_prefill(const float* __restrict__ qkv, float* __restrict__ kc,
                                   float* __restrict__ vc) {
  int bt = blockIdx.x;
  int b = bt / PROMPT_LEN, t = bt % PROMPT_LEN;
  for (int i = threadIdx.x; i < DIM; i += blockDim.x) {
    int h = i / HEADD, d = i % HEADD;
    size_t ci = ((size_t)(b * NHEAD + h) * TMAX + t) * HEADD + d;
    kc[ci] = qkv[(size_t)bt * 3 * DIM + DIM + i];
    vc[ci] = qkv[(size_t)bt * 3 * DIM + 2 * DIM + i];
  }
}

// ---------------- prefill attention ----------------
__global__ void k_attn_prefill(const float* __restrict__ qkv, const float* __restrict__ kc,
                               const float* __restrict__ vc, float* __restrict__ o) {
  int blk = blockIdx.x;
  int q = blk % PROMPT_LEN;
  int bh = blk / PROMPT_LEN;
  int h = bh % NHEAD, b = bh / NHEAD;
  int tid = threadIdx.x;  // 64
  __shared__ float qs[HEADD];
  __shared__ float ps[PROMPT_LEN];
  qs[tid] = qkv[(size_t)(b * PROMPT_LEN + q) * 3 * DIM + h * HEADD + tid];
  __syncthreads();
  const float* kb = kc + (size_t)(b * NHEAD + h) * TMAX * HEADD;
  const float* vb = vc + (size_t)(b * NHEAD + h) * TMAX * HEADD;
  float s = -1e30f;
  if (tid <= q) {
    float a = 0.f;
    for (int d = 0; d < HEADD; ++d) a += qs[d] * kb[tid * HEADD + d];
    s = a * ATT_SCALE;
  }
  float mx = s;
  for (int off = 32; off > 0; off >>= 1) mx = fmaxf(mx, __shfl_xor(mx, off));
  float e = (tid <= q) ? expf(s - mx) : 0.f;
  float sum = e;
  for (int off = 32; off > 0; off >>= 1) sum += __shfl_xor(sum, off);
  ps[tid] = e / sum;
  __syncthreads();
  float acc = 0.f;
  for (int t = 0; t <= q; ++t) acc += ps[t] * vb[t * HEADD + tid];
  o[(size_t)(b * PROMPT_LEN + q) * DIM + h * HEADD + tid] = acc;
}

// ---------------- decode: fused embed + LN1 -> xd, At ----------------
__global__ __launch_bounds__(1024) void k_embed_ln(const int* __restrict__ ids,
                                                   const int* __restrict__ lens,
                                                   const float* __restrict__ wte,
                                                   const float* __restrict__ wpe,
                                                   const float* __restrict__ lnw,
                                                   const float* __restrict__ lnb,
                                                   float* __restrict__ xd, float* __restrict__ At) {
  int b = threadIdx.x >> 6;
  int lane = threadIdx.x & 63;
  int p = lens[b] - 1;
  if (p < 0) p = 0;
  if (p > TMAX - 1) p = TMAX - 1;
  int tok = ids[b * TMAX + p];
  float v[8];
  float s = 0.f;
#pragma unroll
  for (int j = 0; j < 8; ++j) {
    int c = lane + j * 64;
    float t = wte[(size_t)tok * DIM + c] + wpe[(size_t)p * DIM + c];
    v[j] = t;
    s += t;
    xd[(size_t)b * DIM + c] = t;
  }
  for (int off = 32; off > 0; off >>= 1) s += __shfl_xor(s, off);
  float mean = s * (1.0f / DIM);
  float vs = 0.f;
#pragma unroll
  for (int j = 0; j < 8; ++j) {
    float d = v[j] - mean;
    vs += d * d;
  }
  for (int off = 32; off > 0; off >>= 1) vs += __shfl_xor(vs, off);
  float rstd = 1.0f / sqrtf(vs * (1.0f / DIM) + 1e-5f);
#pragma unroll
  for (int j = 0; j < 8; ++j) {
    int c = lane + j * 64;
    At[(size_t)c * BATCH + b] = (v[j] - mean) * rstd * lnw[c] + lnb[c];
  }
}

// ---------------- decode skinny GEMM: C[16,N] = At^T[16,K] @ W[K,N] ----------------
// A is [K][16] transposed activations, staged in LDS (broadcast reads in K-loop).
// In-block split-K over WAVES waves; optional cross-block split-K (KB) -> partials.
// MODE (KB==1): 0 = +bias row-major, 1 = gelu(+bias) transposed out, 3 = plain row-major.
template <int WAVES, int KB, int MODE, int N, int K>
__global__ __launch_bounds__(WAVES * 64) void k_skinny(const float* __restrict__ At,
                                                       const float* __restrict__ W,
                                                       const float* __restrict__ bias,
                                                       float* __restrict__ out) {
  __shared__ float smem[8192];  // 32 KB: A-stage, then reused for cross-wave reduce
  const int tid = threadIdx.x;
  const int lane = tid & 63;
  const int w = tid >> 6;
  const int col = blockIdx.x * 64 + lane;
  const int Krange = K / KB;
  const int k00 = blockIdx.y * Krange;
  const int kchunk = Krange / WAVES;

  // stage A slice [k00, k00+Krange) x 16 (coalesced float4)
  {
    const float4* A4 = (const float4*)(At + (size_t)k00 * BATCH);
    float4* S4 = (float4*)smem;
    const int nf4 = Krange * BATCH / 4;
    for (int i = tid; i < nf4; i += WAVES * 64) S4[i] = A4[i];
  }
  __syncthreads();

  float acc[BATCH];
#pragma unroll
  for (int b = 0; b < BATCH; ++b) acc[b] = 0.f;

  const float* Wp = W + (size_t)(k00 + w * kchunk) * N + col;
  const int rbase = w * kchunk;
  for (int k = 0; k < kchunk; k += 16) {
    float wv[16];
#pragma unroll
    for (int u = 0; u < 16; ++u) wv[u] = Wp[(size_t)(k + u) * N];
#pragma unroll
    for (int u = 0; u < 16; ++u) {
      const float4* a4 = (const float4*)&smem[(rbase + k + u) * BATCH];
      float4 A0 = a4[0], A1 = a4[1], A2 = a4[2], A3 = a4[3];
      acc[0] = fmaf(A0.x, wv[u], acc[0]);
      acc[1] = fmaf(A0.y, wv[u], acc[1]);
      acc[2] = fmaf(A0.z, wv[u], acc[2]);
      acc[3] = fmaf(A0.w, wv[u], acc[3]);
      acc[4] = fmaf(A1.x, wv[u], acc[4]);
      acc[5] = fmaf(A1.y, wv[u], acc[5]);
      acc[6] = fmaf(A1.z, wv[u], acc[6]);
      acc[7] = fmaf(A1.w, wv[u], acc[7]);
      acc[8] = fmaf(A2.x, wv[u], acc[8]);
      acc[9] = fmaf(A2.y, wv[u], acc[9]);
      acc[10] = fmaf(A2.z, wv[u], acc[10]);
      acc[11] = fmaf(A2.w, wv[u], acc[11]);
      acc[12] = fmaf(A3.x, wv[u], acc[12]);
      acc[13] = fmaf(A3.y, wv[u], acc[13]);
      acc[14] = fmaf(A3.z, wv[u], acc[14]);
      acc[15] = fmaf(A3.w, wv[u], acc[15]);
    }
  }
  __syncthreads();  // all waves done reading staged A
#pragma unroll
  for (int b = 0; b < BATCH; ++b) smem[(w * BATCH + b) * 64 + lane] = acc[b];
  __syncthreads();
  for (int o = tid; o < BATCH * 64; o += WAVES * 64) {
    int b = o >> 6, n = o & 63;
    float v = 0.f;
#pragma unroll
    for (int ww = 0; ww < WAVES; ++ww) v += smem[(ww * BATCH + b) * 64 + n];
    int gn = blockIdx.x * 64 + n;
    if (KB > 1) {
      out[((size_t)blockIdx.y * BATCH + b) * N + gn] = v;
    } else if (MODE == 0) {
      out[(size_t)b * N + gn] = v + bias[gn];
    } else if (MODE == 1) {
      out[(size_t)gn * BATCH + b] = gelu_f(v + bias[gn]);
    } else {
      out[(size_t)b * N + gn] = v;
    }
  }
}

// ---------------- decode: reduce KB partials + bias + residual, then LN -> At ----------------
template <int KB>
__global__ __launch_bounds__(1024) void k_reduce_ln(const float* __restrict__ part,
                                                    const float* __restrict__ bias,
                                                    float* __restrict__ xd,
                                                    const float* __restrict__ lnw,
                                                    const float* __restrict__ lnb,
                                                    float* __restrict__ At) {
  int b = threadIdx.x >> 6;
  int lane = threadIdx.x & 63;
  float v[8];
  float s = 0.f;
#pragma unroll
  for (int j = 0; j < 8; ++j) {
    int c = lane + j * 64;
    float t = xd[(size_t)b * DIM + c] + bias[c];
#pragma unroll
    for (int kb = 0; kb < KB; ++kb) t += part[((size_t)kb * BATCH + b) * DIM + c];
    v[j] = t;
    s += t;
    xd[(size_t)b * DIM + c] = t;
  }
  for (int off = 32; off > 0; off >>= 1) s += __shfl_xor(s, off);
  float mean = s * (1.0f / DIM);
  float vs = 0.f;
#pragma unroll
  for (int j = 0; j < 8; ++j) {
    float d = v[j] - mean;
    vs += d * d;
  }
  for (int off = 32; off > 0; off >>= 1) vs += __shfl_xor(vs, off);
  float rstd = 1.0f / sqrtf(vs * (1.0f / DIM) + 1e-5f);
#pragma unroll
  for (int j = 0; j < 8; ++j) {
    int c = lane + j * 64;
    At[(size_t)c * BATCH + b] = (v[j] - mean) * rstd * lnw[c] + lnb[c];
  }
}

// ---------------- decode attention (appends KV), writes Ot transposed ----------------
__global__ void k_attn_decode(const float* __restrict__ qkvd, const int* __restrict__ lens,
                              float* __restrict__ kc, float* __restrict__ vc,
                              float* __restrict__ ot) {
  int h = blockIdx.x % NHEAD, b = blockIdx.x / NHEAD;
  int tid = threadIdx.x;  // 64
  int p = lens[b] - 1;
  if (p < 0) p = 0;
  if (p > TMAX - 1) p = TMAX - 1;
  float kself = qkvd[(size_t)b * 3 * DIM + DIM + h * HEADD + tid];
  float vself = qkvd[(size_t)b * 3 * DIM + 2 * DIM + h * HEADD + tid];
  float* kb = kc + (size_t)(b * NHEAD + h) * TMAX * HEADD;
  float* vb = vc + (size_t)(b * NHEAD + h) * TMAX * HEADD;
  kb[p * HEADD + tid] = kself;
  vb[p * HEADD + tid] = vself;
  __shared__ float qs[HEADD];
  __shared__ float ps[TMAX];
  qs[tid] = qkvd[(size_t)b * 3 * DIM + h * HEADD + tid];
  __syncthreads();
  float pd = qs[tid] * kself;
  for (int off = 32; off > 0; off >>= 1) pd += __shfl_xor(pd, off);
  float selfdot = pd * ATT_SCALE;
  float s0 = -1e30f, s1 = -1e30f;
  int t1 = tid + 64;
  if (tid < p) {
    float a = 0.f;
    for (int d = 0; d < HEADD; ++d) a += qs[d] * kb[tid * HEADD + d];
    s0 = a * ATT_SCALE;
  } else if (tid == p) {
    s0 = selfdot;
  }
  if (t1 < p) {
    float a = 0.f;
    for (int d = 0; d < HEADD; ++d) a += qs[d] * kb[t1 * HEADD + d];
    s1 = a * ATT_SCALE;
  } else if (t1 == p) {
    s1 = selfdot;
  }
  float mx = fmaxf(s0, s1);
  for (int off = 32; off > 0; off >>= 1) mx = fmaxf(mx, __shfl_xor(mx, off));
  float e0 = (tid <= p) ? expf(s0 - mx) : 0.f;
  float e1 = (t1 <= p) ? expf(s1 - mx) : 0.f;
  float sum = e0 + e1;
  for (int off = 32; off > 0; off >>= 1) sum += __shfl_xor(sum, off);
  float inv = 1.f / sum;
  ps[tid] = e0 * inv;
  if (tid < TMAX - 64) ps[t1] = e1 * inv;
  __syncthreads();
  float acc = 0.f;
  for (int t = 0; t < p; ++t) acc += ps[t] * vb[t * HEADD + tid];
  acc += ps[p] * vself;
  ot[(size_t)(h * HEADD + tid) * BATCH + b] = acc;
}

// ---------------- per-step state update ----------------
__global__ void k_update(const float* __restrict__ logits, int* __restrict__ ids,
                         int* __restrict__ lens, int* __restrict__ fin, float* __restrict__ csum,
                         float* __restrict__ ccnt, float* __restrict__ out_gen, int step) {
  int b = blockIdx.x, tid = threadIdx.x;
  const float* lr = logits + (size_t)b * VOCAB;
  __shared__ float vred[256];
  __shared__ int ired[256];
  float best = -1e30f;
  int besti = 0;
  for (int i = tid; i < VOCAB; i += 256) {
    float v = lr[i];
    if (v > best) {
      best = v;
      besti = i;
    }
  }
  vred[tid] = best;
  ired[tid] = besti;
  __syncthreads();
  for (int s = 128; s > 0; s >>= 1) {
    if (tid < s) {
      if (vred[tid + s] > vred[tid] ||
          (vred[tid + s] == vred[tid] && ired[tid + s] < ired[tid])) {
        vred[tid] = vred[tid + s];
        ired[tid] = ired[tid + s];
      }
    }
    __syncthreads();
  }
  float mx = vred[0];
  int top = ired[0];
  __syncthreads();
  float se = 0.f;
  for (int i = tid; i < VOCAB; i += 256) se += expf(lr[i] - mx);
  vred[tid] = se;
  __syncthreads();
  for (int s = 128; s > 0; s >>= 1) {
    if (tid < s) vred[tid] += vred[tid + s];
    __syncthreads();
  }
  if (tid == 0) {
    float top_p = 1.f / vred[0];
    int l = lens[b];
    bool active = (!fin[b]) && (l < TMAX);
    if (active) {
      csum[b] += top_p;
      ccnt[b] += 1.f;
    }
    bool is_end = (top == 3) || (top == 0);
    bool wr = active && !is_end;
    if (wr) {
      ids[b * TMAX + l] = top;
      lens[b] = l + 1;
    }
    if (active && is_end) fin[b] = 1;
    out_gen[b * NNEW + step] = wr ? (float)top : 0.f;
  }
}

__global__ void k_finalize(const float* __restrict__ csum, const float* __restrict__ ccnt,
                           float* __restrict__ out) {
  int b = threadIdx.x;
  if (b < BATCH) out[BATCH * NNEW + b] = csum[b] / fmaxf(ccnt[b], 1.f);
}

// ---------------- host launch ----------------
extern "C" void kernel_launch(void* const* d_in, const int* in_sizes, int n_in, void* d_out,
                              int out_size, void* d_ws, size_t ws_size, hipStream_t stream) {
  const float* wte = (const float*)d_in[0];
  const float* wpe = (const float*)d_in[1];
  const float* ln1_w = (const float*)d_in[2];
  const float* ln1_b = (const float*)d_in[3];
  const float* qkv_w = (const float*)d_in[4];
  const float* qkv_b = (const float*)d_in[5];
  const float* ao_w = (const float*)d_in[6];
  const float* ao_b = (const float*)d_in[7];
  const float* ln2_w = (const float*)d_in[8];
  const float* ln2_b = (const float*)d_in[9];
  const float* fc_w = (const float*)d_in[10];
  const float* fc_b = (const float*)d_in[11];
  const float* pr_w = (const float*)d_in[12];
  const float* pr_b = (const float*)d_in[13];
  const float* lnf_w = (const float*)d_in[14];
  const float* lnf_b = (const float*)d_in[15];
  const float* lm_w = (const float*)d_in[16];
  const int* ids_in = (const int*)d_in[17];
  const int* mask_in = (const int*)d_in[18];
  float* out = (float*)d_out;

  char* p = (char*)d_ws;
  auto carve = [&](size_t nbytes) {
    char* r = p;
    p += (nbytes + 255) & ~(size_t)255;
    return (void*)r;
  };
  int* w_ids = (int*)carve(BATCH * TMAX * 4);
  int* w_lens = (int*)carve(BATCH * 4);
  int* w_fin = (int*)carve(BATCH * 4);
  float* w_csum = (float*)carve(BATCH * 4);
  float* w_ccnt = (float*)carve(BATCH * 4);
  float* w_x = (float*)carve((size_t)BATCH * PROMPT_LEN * DIM * 4);
  float* w_h = (float*)carve((size_t)BATCH * PROMPT_LEN * DIM * 4);
  float* w_qkv = (float*)carve((size_t)BATCH * PROMPT_LEN * 3 * DIM * 4);
  float* w_att = (float*)carve((size_t)BATCH * PROMPT_LEN * DIM * 4);
  float* w_mlp = (float*)carve((size_t)BATCH * PROMPT_LEN * 4 * DIM * 4);
  float* w_kc = (float*)carve((size_t)NLAYER * BATCH * NHEAD * TMAX * HEADD * 4);
  float* w_vc = (float*)carve((size_t)NLAYER * BATCH * NHEAD * TMAX * HEADD * 4);
  float* w_xd = (float*)carve(BATCH * DIM * 4);
  float* w_at = (float*)carve((size_t)DIM * BATCH * 4);      // At[512][16]
  float* w_qkvd = (float*)carve(BATCH * 3 * DIM * 4);
  float* w_ot = (float*)carve((size_t)DIM * BATCH * 4);      // Ot[512][16]
  float* w_gt = (float*)carve((size_t)4 * DIM * BATCH * 4);  // Gt[2048][16]
  float* w_part = (float*)carve((size_t)4 * BATCH * DIM * 4);
  float* w_logits = (float*)carve((size_t)BATCH * VOCAB * 4);

  const int M = BATCH * PROMPT_LEN;  // 1024
  const size_t kvstride = (size_t)BATCH * NHEAD * TMAX * HEADD;

  k_init<<<1, 256, 0, stream>>>(ids_in, mask_in, w_ids, w_lens, w_fin, w_csum, w_ccnt);
  k_embed_prefill<<<M, 256, 0, stream>>>(w_ids, wte, wpe, w_x);

  for (int l = 0; l < NLAYER; ++l) {
    float* kc = w_kc + (size_t)l * kvstride;
    float* vc = w_vc + (size_t)l * kvstride;
    k_layernorm<<<M, 256, 0, stream>>>(w_x, ln1_w + l * DIM, ln1_b + l * DIM, w_h);
    gemm_kernel<0><<<dim3(3 * DIM / 64, M / 64), 256, 0, stream>>>(
        w_h, qkv_w + (size_t)l * DIM * 3 * DIM, qkv_b + (size_t)l * 3 * DIM, nullptr, w_qkv, M,
        3 * DIM, DIM);
    k_write_kv_prefill<<<M, 128, 0, stream>>>(w_qkv, kc, vc);
    k_attn_prefill<<<BATCH * NHEAD * PROMPT_LEN, 64, 0, stream>>>(w_qkv, kc, vc, w_att);
    gemm_kernel<2><<<dim3(DIM / 64, M / 64), 256, 0, stream>>>(
        w_att, ao_w + (size_t)l * DIM * DIM, ao_b + (size_t)l * DIM, w_x, w_x, M, DIM, DIM);
    k_layernorm<<<M, 256, 0, stream>>>(w_x, ln2_w + l * DIM, ln2_b + l * DIM, w_h);
    gemm_kernel<1><<<dim3(4 * DIM / 64, M / 64), 256, 0, stream>>>(
        w_h, fc_w + (size_t)l * DIM * 4 * DIM, fc_b + (size_t)l * 4 * DIM, nullptr, w_mlp, M,
        4 * DIM, DIM);
    gemm_kernel<2><<<dim3(DIM / 64, M / 64), 256, 0, stream>>>(
        w_mlp, pr_w + (size_t)l * 4 * DIM * DIM, pr_b + (size_t)l * DIM, w_x, w_x, M, DIM,
        4 * DIM);
  }

  for (int s = 0; s < NNEW; ++s) {
    k_embed_ln<<<1, 1024, 0, stream>>>(w_ids, w_lens, wte, wpe, ln1_w, ln1_b, w_xd, w_at);
    for (int l = 0; l < NLAYER; ++l) {
      float* kc = w_kc + (size_t)l * kvstride;
      float* vc = w_vc + (size_t)l * kvstride;
      // QKV [16,1536]
      k_skinny<8, 1, 0, 3 * DIM, DIM><<<dim3(3 * DIM / 64, 1), 512, 0, stream>>>(
          w_at, qkv_w + (size_t)l * DIM * 3 * DIM, qkv_b + (size_t)l * 3 * DIM, w_qkvd);
      // attention -> Ot[512][16]
      k_attn_decode<<<BATCH * NHEAD, 64, 0, stream>>>(w_qkvd, w_lens, kc, vc, w_ot);
      // AO partials (KB=2)
      k_skinny<8, 2, 9, DIM, DIM><<<dim3(DIM / 64, 2), 512, 0, stream>>>(
          w_ot, ao_w + (size_t)l * DIM * DIM, nullptr, w_part);
      // reduce + residual + LN2 -> At
      k_reduce_ln<2><<<1, 1024, 0, stream>>>(w_part, ao_b + l * DIM, w_xd, ln2_w + l * DIM,
                                             ln2_b + l * DIM, w_at);
      // FC -> Gt[2048][16] (gelu, transposed)
      k_skinny<8, 1, 1, 4 * DIM, DIM><<<dim3(4 * DIM / 64, 1), 512, 0, stream>>>(
          w_at, fc_w + (size_t)l * DIM * 4 * DIM, fc_b + (size_t)l * 4 * DIM, w_gt);
      // PR partials (KB=4)
      k_skinny<8, 4, 9, DIM, 4 * DIM><<<dim3(DIM / 64, 4), 512, 0, stream>>>(
          w_gt, pr_w + (size_t)l * 4 * DIM * DIM, nullptr, w_part);
      // reduce + residual + next LN (ln1[l+1] or lnf) -> At
      const float* nw = (l < NLAYER - 1) ? (ln1_w + (l + 1) * DIM) : lnf_w;
      const float* nb = (l < NLAYER - 1) ? (ln1_b + (l + 1) * DIM) : lnf_b;
      k_reduce_ln<4><<<1, 1024, 0, stream>>>(w_part, pr_b + l * DIM, w_xd, nw, nb, w_at);
    }
    // logits = At^T @ lm_w
    k_skinny<8, 1, 3, VOCAB, DIM><<<dim3(VOCAB / 64, 1), 512, 0, stream>>>(w_at, lm_w, nullptr,
                                                                           w_logits);
    k_update<<<BATCH, 256, 0, stream>>>(w_logits, w_ids, w_lens, w_fin, w_csum, w_ccnt, out, s);
  }
  k_finalize<<<1, 64, 0, stream>>>(w_csum, w_ccnt, out);
}

// Round 4
// 12122.005 us; speedup vs baseline: 7.1862x; 1.1317x over previous
//
#include <hip/hip_runtime.h>
#include <math.h>

#define VOCAB 8000
#define DIM 512
#define NLAYER 8
#define NHEAD 8
#define BATCH 16
#define TMAX 80
#define PROMPT_LEN 64
#define NNEW 16
#define HEADD 64
#define ATT_SCALE 0.125f

#define SRC_PLAIN 0
#define SRC_LN 1
#define SRC_GELU 2

__device__ __forceinline__ float gelu_f(float x) {
  return 0.5f * x * (1.0f + tanhf(0.7978845608028654f * (x + 0.044715f * x * x * x)));
}

// ---------------- init ----------------
__global__ void k_init(const int* __restrict__ ids_in, const int* __restrict__ mask_in,
                       int* __restrict__ ids, int* __restrict__ lens, int* __restrict__ fin,
                       float* __restrict__ csum, float* __restrict__ ccnt) {
  int tid = threadIdx.x;
  for (int i = tid; i < BATCH * TMAX; i += blockDim.x) ids[i] = ids_in[i];
  if (tid < BATCH) {
    int s = 0;
    for (int t = 0; t < TMAX; ++t) s += mask_in[tid * TMAX + t];
    lens[tid] = s;
    fin[tid] = 0;
    csum[tid] = 0.f;
    ccnt[tid] = 0.f;
  }
}

// ---------------- prefill embedding ----------------
__global__ void k_embed_prefill(const int* __restrict__ ids, const float* __restrict__ wte,
                                const float* __restrict__ wpe, float* __restrict__ x) {
  int bt = blockIdx.x;
  int b = bt / PROMPT_LEN, t = bt % PROMPT_LEN;
  int tok = ids[b * TMAX + t];
  for (int d = threadIdx.x; d < DIM; d += blockDim.x)
    x[(size_t)bt * DIM + d] = wte[(size_t)tok * DIM + d] + wpe[(size_t)t * DIM + d];
}

// ---------------- prefill layernorm ----------------
__global__ void k_layernorm(const float* __restrict__ x, const float* __restrict__ w,
                            const float* __restrict__ b, float* __restrict__ out) {
  int row = blockIdx.x;
  int tid = threadIdx.x;
  const float* xr = x + (size_t)row * DIM;
  __shared__ float red[256];
  float v0 = xr[tid], v1 = xr[tid + 256];
  red[tid] = v0 + v1;
  __syncthreads();
  for (int s = 128; s > 0; s >>= 1) {
    if (tid < s) red[tid] += red[tid + s];
    __syncthreads();
  }
  float mean = red[0] * (1.0f / DIM);
  __syncthreads();
  float d0 = v0 - mean, d1 = v1 - mean;
  red[tid] = d0 * d0 + d1 * d1;
  __syncthreads();
  for (int s = 128; s > 0; s >>= 1) {
    if (tid < s) red[tid] += red[tid + s];
    __syncthreads();
  }
  float rstd = 1.0f / sqrtf(red[0] * (1.0f / DIM) + 1e-5f);
  out[(size_t)row * DIM + tid] = d0 * rstd * w[tid] + b[tid];
  out[(size_t)row * DIM + tid + 256] = d1 * rstd * w[tid + 256] + b[tid + 256];
}

// ---------------- prefill tiled GEMM ----------------
// MODE: 1 = gelu(+bias), 2 = +bias +res, 3 = qkv epilogue (+bias, write q + KV caches)
template <int MODE>
__global__ __launch_bounds__(256) void gemm_kernel(const float* __restrict__ A,
                                                   const float* __restrict__ W,
                                                   const float* __restrict__ bias,
                                                   const float* __restrict__ res,
                                                   float* __restrict__ C, int M, int N, int K,
                                                   float* __restrict__ kcT,
                                                   float* __restrict__ vc) {
  const int BM = 64, BN = 64, BK = 16;
  __shared__ float As[BK][BM + 4];
  __shared__ float Ws[BK][BN];
  int tid = threadIdx.x;
  int bm = blockIdx.y * BM, bn = blockIdx.x * BN;
  int tr = tid / 16, tc = tid % 16;
  float acc[4][4];
#pragma unroll
  for (int i = 0; i < 4; i++)
#pragma unroll
    for (int j = 0; j < 4; j++) acc[i][j] = 0.f;

  for (int k0 = 0; k0 < K; k0 += BK) {
    for (int i = tid; i < BM * BK; i += 256) {
      int m = i / BK, kk = i % BK;
      As[kk][m] = A[(size_t)(bm + m) * K + k0 + kk];
    }
    for (int i = tid; i < BK * BN; i += 256) {
      int kk = i / BN, n = i % BN;
      Ws[kk][n] = W[(size_t)(k0 + kk) * N + bn + n];
    }
    __syncthreads();
#pragma unroll
    for (int kk = 0; kk < BK; ++kk) {
      float a[4], w[4];
#pragma unroll
      for (int i = 0; i < 4; i++) a[i] = As[kk][tr * 4 + i];
#pragma unroll
      for (int j = 0; j < 4; j++) w[j] = Ws[kk][tc * 4 + j];
#pragma unroll
      for (int i = 0; i < 4; i++)
#pragma unroll
        for (int j = 0; j < 4; j++) acc[i][j] += a[i] * w[j];
    }
    __syncthreads();
  }
#pragma unroll
  for (int i = 0; i < 4; i++) {
    int m = bm + tr * 4 + i;
#pragma unroll
    for (int j = 0; j < 4; j++) {
      int n = bn + tc * 4 + j;
      float v = acc[i][j] + (bias ? bias[n] : 0.f);
      if (MODE == 1) v = gelu_f(v);
      if (MODE == 2) v += res[(size_t)m * N + n];
      if (MODE == 3) {
        int b = m >> 6, t = m & 63;
        if (n < DIM) {
          C[(size_t)m * N + n] = v;  // q (only q region consumed)
        } else if (n < 2 * DIM) {
          int dd = n - DIM;
          kcT[((size_t)(b * NHEAD + (dd >> 6)) * HEADD + (dd & 63)) * TMAX + t] = v;
        } else {
          int dd = n - 2 * DIM;
          vc[((size_t)(b * NHEAD + (dd >> 6)) * TMAX + t) * HEADD + (dd & 63)] = v;
        }
      } else {
        C[(size_t)m * N + n] = v;
      }
    }
  }
}

// ---------------- prefill attention (K^T cache layout) ----------------
__global__ void k_attn_prefill(const float* __restrict__ qkv, const float* __restrict__ kcT,
                               const float* __restrict__ vc, float* __restrict__ o) {
  int blk = blockIdx.x;
  int q = blk % PROMPT_LEN;
  int bh = blk / PROMPT_LEN;
  int h = bh % NHEAD, b = bh / NHEAD;
  int tid = threadIdx.x;  // 64
  __shared__ float qs[HEADD];
  __shared__ float ps[PROMPT_LEN];
  qs[tid] = qkv[(size_t)(b * PROMPT_LEN + q) * 3 * DIM + h * HEADD + tid];
  __syncthreads();
  const float* kbT = kcT + (size_t)(b * NHEAD + h) * HEADD * TMAX;  // [64][80]
  const float* vb = vc + (size_t)(b * NHEAD + h) * TMAX * HEADD;    // [80][64]
  float s = -1e30f;
  if (tid <= q) {
    float a = 0.f;
    for (int d = 0; d < HEADD; ++d) a += qs[d] * kbT[d * TMAX + tid];
    s = a * ATT_SCALE;
  }
  float mx = s;
  for (int off = 32; off > 0; off >>= 1) mx = fmaxf(mx, __shfl_xor(mx, off));
  float e = (tid <= q) ? expf(s - mx) : 0.f;
  float sum = e;
  for (int off = 32; off > 0; off >>= 1) sum += __shfl_xor(sum, off);
  ps[tid] = e / sum;
  __syncthreads();
  float acc = 0.f;
  for (int t = 0; t <= q; ++t) acc += ps[t] * vb[t * HEADD + tid];
  o[(size_t)(b * PROMPT_LEN + q) * DIM + h * HEADD + tid] = acc;
}

// ---------------- decode: initial embedding -> xd0 (transposed [512][16]) ----------------
__global__ void k_embed0(const int* __restrict__ ids, const int* __restrict__ lens,
                         const float* __restrict__ wte, const float* __restrict__ wpe,
                         float* __restrict__ xdT) {
  int b = blockIdx.x;
  int p = lens[b] - 1;
  if (p < 0) p = 0;
  if (p > TMAX - 1) p = TMAX - 1;
  int tok = ids[b * TMAX + p];
  for (int d = threadIdx.x; d < DIM; d += blockDim.x)
    xdT[(size_t)d * BATCH + b] = wte[(size_t)tok * DIM + d] + wpe[(size_t)p * DIM + d];
}

// ---------------- decode skinny GEMM with fused stage ----------------
// C[16,N] = A^T[16,K] @ W[K,N]. A ([K][16]) is built in LDS from:
//   SRC_PLAIN: src            SRC_LN: ln(src + sum parts) (full-K stage; opt. write xd)
//   SRC_GELU: gelu(sum parts)
// 8 waves = 2 batch-groups x 4 k-chunks. KB = cross-block split-K (partials out,
// bias folded into partial kb==0). LAYOUT: 0 row-major [kb][16][N], 1 transposed [kb][N][16].
template <int KB, int SRC, int P, int LAYOUT, bool BIAS, bool XDW, int N, int K>
__global__ __launch_bounds__(512) void k_skinny(const float* __restrict__ src,
                                                const float* __restrict__ parts,
                                                const float* __restrict__ lnw,
                                                const float* __restrict__ lnb,
                                                const float* __restrict__ bias,
                                                const float* __restrict__ W,
                                                float* __restrict__ out,
                                                float* __restrict__ xdout) {
  constexpr int KRANGE = K / KB;
  constexpr int SROWS = (SRC == SRC_LN) ? K : KRANGE;
  __shared__ float sm[SROWS * BATCH];
  __shared__ float wsum[8][BATCH];
  __shared__ float wss[8][BATCH];
  __shared__ float smean[BATCH], srstd[BATCH];
  const int tid = threadIdx.x;
  const int base_row = (SRC == SRC_LN) ? 0 : blockIdx.y * KRANGE;

  // ---- stage ----
  {
    const float4* s4 = (const float4*)src;
    float4* d4 = (float4*)sm;
    constexpr int NF4 = SROWS * BATCH / 4;
    for (int i = tid; i < NF4; i += 512) {
      int gi = base_row * (BATCH / 4) + i;
      float4 v;
      if (SRC == SRC_GELU) {
        v = make_float4(0.f, 0.f, 0.f, 0.f);
      } else {
        v = s4[gi];
      }
#pragma unroll
      for (int p = 0; p < P; ++p) {
        const float4* p4 = (const float4*)(parts + (size_t)p * K * BATCH);
        float4 t = p4[gi];
        v.x += t.x;
        v.y += t.y;
        v.z += t.z;
        v.w += t.w;
      }
      if (SRC == SRC_GELU) {
        v.x = gelu_f(v.x);
        v.y = gelu_f(v.y);
        v.z = gelu_f(v.z);
        v.w = gelu_f(v.w);
      }
      if (XDW) {
        if (blockIdx.x == 0 && blockIdx.y == 0) ((float4*)xdout)[gi] = v;
      }
      d4[i] = v;
    }
  }
  if (SRC == SRC_LN) {
    __syncthreads();
    float s = 0.f, ss = 0.f;
#pragma unroll
    for (int j = 0; j < 16; ++j) {
      float v = sm[tid + 512 * j];
      s += v;
      ss += v * v;
    }
    s += __shfl_xor(s, 16);
    ss += __shfl_xor(ss, 16);
    s += __shfl_xor(s, 32);
    ss += __shfl_xor(ss, 32);
    int lane0 = tid & 63, w0 = tid >> 6;
    if (lane0 < BATCH) {
      wsum[w0][lane0] = s;
      wss[w0][lane0] = ss;
    }
    __syncthreads();
    if (tid < BATCH) {
      float ts = 0.f, tss = 0.f;
#pragma unroll
      for (int ww = 0; ww < 8; ++ww) {
        ts += wsum[ww][tid];
        tss += wss[ww][tid];
      }
      float m = ts * (1.0f / K);
      float var = tss * (1.0f / K) - m * m;
      smean[tid] = m;
      srstd[tid] = 1.0f / sqrtf(var + 1e-5f);
    }
    __syncthreads();
    float mb = smean[tid & 15];
    float rb = srstd[tid & 15];
#pragma unroll
    for (int j = 0; j < 16; ++j) {
      int idx = tid + 512 * j;
      int k = idx >> 4;
      sm[idx] = (sm[idx] - mb) * rb * lnw[k] + lnb[k];
    }
  }
  __syncthreads();

  // ---- K-loop ----
  const int lane = tid & 63;
  const int w = tid >> 6;
  const int bw = w & 1;
  const int kw = w >> 1;
  constexpr int KCH = KRANGE / 4;
  const int col = blockIdx.x * 64 + lane;
  const float* Wp = W + (size_t)(blockIdx.y * KRANGE + kw * KCH) * N + col;
  const int fbase = ((SRC == SRC_LN) ? blockIdx.y * KRANGE : 0) + kw * KCH;
  float acc[8];
#pragma unroll
  for (int i = 0; i < 8; ++i) acc[i] = 0.f;
  for (int k = 0; k < KCH; k += 8) {
    float wv[8];
#pragma unroll
    for (int u = 0; u < 8; ++u) wv[u] = Wp[(size_t)(k + u) * N];
#pragma unroll
    for (int u = 0; u < 8; ++u) {
      const float4* a4 = (const float4*)&sm[(fbase + k + u) * BATCH + bw * 8];
      float4 A0 = a4[0], A1 = a4[1];
      acc[0] = fmaf(A0.x, wv[u], acc[0]);
      acc[1] = fmaf(A0.y, wv[u], acc[1]);
      acc[2] = fmaf(A0.z, wv[u], acc[2]);
      acc[3] = fmaf(A0.w, wv[u], acc[3]);
      acc[4] = fmaf(A1.x, wv[u], acc[4]);
      acc[5] = fmaf(A1.y, wv[u], acc[5]);
      acc[6] = fmaf(A1.z, wv[u], acc[6]);
      acc[7] = fmaf(A1.w, wv[u], acc[7]);
    }
  }
  __syncthreads();
#pragma unroll
  for (int i = 0; i < 8; ++i) sm[(w * 8 + i) * 64 + lane] = acc[i];
  __syncthreads();
  for (int o = tid; o < BATCH * 64; o += 512) {
    int b, gn_l;
    if (LAYOUT == 1) {
      b = o & 15;
      gn_l = o >> 4;
    } else {
      b = o >> 6;
      gn_l = o & 63;
    }
    int bw2 = b >> 3, bi = b & 7;
    float v = 0.f;
#pragma unroll
    for (int k2 = 0; k2 < 4; ++k2) v += sm[(((k2 * 2 + bw2) * 8) + bi) * 64 + gn_l];
    int gn = blockIdx.x * 64 + gn_l;
    if (BIAS && blockIdx.y == 0) v += bias[gn];
    if (KB == 1 && LAYOUT == 0)
      out[(size_t)b * N + gn] = v;
    else if (LAYOUT == 0)
      out[((size_t)blockIdx.y * BATCH + b) * N + gn] = v;
    else
      out[(size_t)blockIdx.y * N * BATCH + (size_t)gn * BATCH + b] = v;
  }
}

// ---------------- decode attention: sums qkv partials, appends KV, Ot transposed ----------------
__global__ void k_attn_decode(const float* __restrict__ qp, const int* __restrict__ lens,
                              float* __restrict__ kcT, float* __restrict__ vc,
                              float* __restrict__ ot) {
  int h = blockIdx.x % NHEAD, b = blockIdx.x / NHEAD;
  int d = threadIdx.x;  // 64
  int p = lens[b] - 1;
  if (p < 0) p = 0;
  if (p > TMAX - 1) p = TMAX - 1;
  const float* q0 = qp + (size_t)b * 3 * DIM + h * HEADD;
  const float* q1 = qp + (size_t)BATCH * 3 * DIM + (size_t)b * 3 * DIM + h * HEADD;
  float qv = q0[d] + q1[d];
  float kself = q0[DIM + d] + q1[DIM + d];
  float vself = q0[2 * DIM + d] + q1[2 * DIM + d];
  float* kT = kcT + (size_t)(b * NHEAD + h) * HEADD * TMAX;  // [64][80]
  float* vb = vc + (size_t)(b * NHEAD + h) * TMAX * HEADD;   // [80][64]
  kT[d * TMAX + p] = kself;
  vb[p * HEADD + d] = vself;
  __shared__ float qs[HEADD];
  __shared__ float ps[TMAX];
  qs[d] = qv;
  __syncthreads();
  float pd = qv * kself;
  for (int off = 32; off > 0; off >>= 1) pd += __shfl_xor(pd, off);
  float selfdot = pd * ATT_SCALE;
  float s0 = -1e30f, s1 = -1e30f;
  int t1 = d + 64;
  if (d < p) {
    float a = 0.f;
    for (int dd = 0; dd < HEADD; ++dd) a += qs[dd] * kT[dd * TMAX + d];
    s0 = a * ATT_SCALE;
  } else if (d == p) {
    s0 = selfdot;
  }
  if (t1 < p) {
    float a = 0.f;
    for (int dd = 0; dd < HEADD; ++dd) a += qs[dd] * kT[dd * TMAX + t1];
    s1 = a * ATT_SCALE;
  } else if (t1 == p) {
    s1 = selfdot;
  }
  float mx = fmaxf(s0, s1);
  for (int off = 32; off > 0; off >>= 1) mx = fmaxf(mx, __shfl_xor(mx, off));
  float e0 = (d <= p) ? expf(s0 - mx) : 0.f;
  float e1 = (t1 <= p) ? expf(s1 - mx) : 0.f;
  float sum = e0 + e1;
  for (int off = 32; off > 0; off >>= 1) sum += __shfl_xor(sum, off);
  float inv = 1.f / sum;
  ps[d] = e0 * inv;
  if (d < TMAX - 64) ps[t1] = e1 * inv;
  __syncthreads();
  float acc = 0.f;
  for (int t = 0; t < p; ++t) acc += ps[t] * vb[t * HEADD + d];
  acc += ps[p] * vself;
  ot[(size_t)(h * HEADD + d) * BATCH + b] = acc;
}

// ---------------- final LN: At = lnf(xd1 + sum of 4 pr partials) ----------------
__global__ __launch_bounds__(512) void k_lnf(const float* __restrict__ xd,
                                             const float* __restrict__ parts,
                                             const float* __restrict__ lnw,
                                             const float* __restrict__ lnb,
                                             float* __restrict__ At) {
  __shared__ float sm[DIM * BATCH];
  __shared__ float wsum[8][BATCH];
  __shared__ float wss[8][BATCH];
  __shared__ float smean[BATCH], srstd[BATCH];
  const int tid = threadIdx.x;
  {
    const float4* s4 = (const float4*)xd;
    float4* d4 = (float4*)sm;
    for (int i = tid; i < DIM * BATCH / 4; i += 512) {
      float4 v = s4[i];
#pragma unroll
      for (int p = 0; p < 4; ++p) {
        const float4* p4 = (const float4*)(parts + (size_t)p * DIM * BATCH);
        float4 t = p4[i];
        v.x += t.x;
        v.y += t.y;
        v.z += t.z;
        v.w += t.w;
      }
      d4[i] = v;
    }
  }
  __syncthreads();
  float s = 0.f, ss = 0.f;
#pragma unroll
  for (int j = 0; j < 16; ++j) {
    float v = sm[tid + 512 * j];
    s += v;
    ss += v * v;
  }
  s += __shfl_xor(s, 16);
  ss += __shfl_xor(ss, 16);
  s += __shfl_xor(s, 32);
  ss += __shfl_xor(ss, 32);
  int lane0 = tid & 63, w0 = tid >> 6;
  if (lane0 < BATCH) {
    wsum[w0][lane0] = s;
    wss[w0][lane0] = ss;
  }
  __syncthreads();
  if (tid < BATCH) {
    float ts = 0.f, tss = 0.f;
#pragma unroll
    for (int ww = 0; ww < 8; ++ww) {
      ts += wsum[ww][tid];
      tss += wss[ww][tid];
    }
    float m = ts * (1.0f / DIM);
    float var = tss * (1.0f / DIM) - m * m;
    smean[tid] = m;
    srstd[tid] = 1.0f / sqrtf(var + 1e-5f);
  }
  __syncthreads();
  float mb = smean[tid & 15];
  float rb = srstd[tid & 15];
#pragma unroll
  for (int j = 0; j < 16; ++j) {
    int idx = tid + 512 * j;
    int k = idx >> 4;
    At[idx] = (sm[idx] - mb) * rb * lnw[k] + lnb[k];
  }
}

// ---------------- per-step state update + next-step embedding ----------------
__global__ void k_update(const float* __restrict__ logits, int* __restrict__ ids,
                         int* __restrict__ lens, int* __restrict__ fin, float* __restrict__ csum,
                         float* __restrict__ ccnt, float* __restrict__ out_gen, int step,
                         const float* __restrict__ wte, const float* __restrict__ wpe,
                         float* __restrict__ xdT) {
  int b = blockIdx.x, tid = threadIdx.x;
  const float* lr = logits + (size_t)b * VOCAB;
  __shared__ float vred[256];
  __shared__ int ired[256];
  __shared__ int sh_tok, sh_pos;
  float best = -1e30f;
  int besti = 0;
  for (int i = tid; i < VOCAB; i += 256) {
    float v = lr[i];
    if (v > best) {
      best = v;
      besti = i;
    }
  }
  vred[tid] = best;
  ired[tid] = besti;
  __syncthreads();
  for (int s = 128; s > 0; s >>= 1) {
    if (tid < s) {
      if (vred[tid + s] > vred[tid] ||
          (vred[tid + s] == vred[tid] && ired[tid + s] < ired[tid])) {
        vred[tid] = vred[tid + s];
        ired[tid] = ired[tid + s];
      }
    }
    __syncthreads();
  }
  float mx = vred[0];
  int top = ired[0];
  __syncthreads();
  float se = 0.f;
  for (int i = tid; i < VOCAB; i += 256) se += expf(lr[i] - mx);
  vred[tid] = se;
  __syncthreads();
  for (int s = 128; s > 0; s >>= 1) {
    if (tid < s) vred[tid] += vred[tid + s];
    __syncthreads();
  }
  if (tid == 0) {
    float top_p = 1.f / vred[0];
    int l = lens[b];
    bool active = (!fin[b]) && (l < TMAX);
    if (active) {
      csum[b] += top_p;
      ccnt[b] += 1.f;
    }
    bool is_end = (top == 3) || (top == 0);
    bool wr = active && !is_end;
    if (wr) {
      ids[b * TMAX + l] = top;
      lens[b] = l + 1;
    }
    if (active && is_end) fin[b] = 1;
    out_gen[b * NNEW + step] = wr ? (float)top : 0.f;
    int l2 = lens[b];
    int pn = l2 - 1;
    if (pn < 0) pn = 0;
    if (pn > TMAX - 1) pn = TMAX - 1;
    sh_pos = pn;
    sh_tok = ids[b * TMAX + pn];
  }
  __syncthreads();
  int tok = sh_tok, pn = sh_pos;
  xdT[(size_t)tid * BATCH + b] = wte[(size_t)tok * DIM + tid] + wpe[(size_t)pn * DIM + tid];
  xdT[(size_t)(tid + 256) * BATCH + b] =
      wte[(size_t)tok * DIM + tid + 256] + wpe[(size_t)pn * DIM + tid + 256];
}

__global__ void k_finalize(const float* __restrict__ csum, const float* __restrict__ ccnt,
                           float* __restrict__ out) {
  int b = threadIdx.x;
  if (b < BATCH) out[BATCH * NNEW + b] = csum[b] / fmaxf(ccnt[b], 1.f);
}

// ---------------- host launch ----------------
extern "C" void kernel_launch(void* const* d_in, const int* in_sizes, int n_in, void* d_out,
                              int out_size, void* d_ws, size_t ws_size, hipStream_t stream) {
  const float* wte = (const float*)d_in[0];
  const float* wpe = (const float*)d_in[1];
  const float* ln1_w = (const float*)d_in[2];
  const float* ln1_b = (const float*)d_in[3];
  const float* qkv_w = (const float*)d_in[4];
  const float* qkv_b = (const float*)d_in[5];
  const float* ao_w = (const float*)d_in[6];
  const float* ao_b = (const float*)d_in[7];
  const float* ln2_w = (const float*)d_in[8];
  const float* ln2_b = (const float*)d_in[9];
  const float* fc_w = (const float*)d_in[10];
  const float* fc_b = (const float*)d_in[11];
  const float* pr_w = (const float*)d_in[12];
  const float* pr_b = (const float*)d_in[13];
  const float* lnf_w = (const float*)d_in[14];
  const float* lnf_b = (const float*)d_in[15];
  const float* lm_w = (const float*)d_in[16];
  const int* ids_in = (const int*)d_in[17];
  const int* mask_in = (const int*)d_in[18];
  float* out = (float*)d_out;

  char* p = (char*)d_ws;
  auto carve = [&](size_t nbytes) {
    char* r = p;
    p += (nbytes + 255) & ~(size_t)255;
    return (void*)r;
  };
  int* w_ids = (int*)carve(BATCH * TMAX * 4);
  int* w_lens = (int*)carve(BATCH * 4);
  int* w_fin = (int*)carve(BATCH * 4);
  float* w_csum = (float*)carve(BATCH * 4);
  float* w_ccnt = (float*)carve(BATCH * 4);
  float* w_x = (float*)carve((size_t)BATCH * PROMPT_LEN * DIM * 4);
  float* w_h = (float*)carve((size_t)BATCH * PROMPT_LEN * DIM * 4);
  float* w_qkv = (float*)carve((size_t)BATCH * PROMPT_LEN * 3 * DIM * 4);
  float* w_att = (float*)carve((size_t)BATCH * PROMPT_LEN * DIM * 4);
  float* w_mlp = (float*)carve((size_t)BATCH * PROMPT_LEN * 4 * DIM * 4);
  float* w_kc = (float*)carve((size_t)NLAYER * BATCH * NHEAD * TMAX * HEADD * 4);
  float* w_vc = (float*)carve((size_t)NLAYER * BATCH * NHEAD * TMAX * HEADD * 4);
  float* w_xd0 = (float*)carve((size_t)DIM * BATCH * 4);
  float* w_xd1 = (float*)carve((size_t)DIM * BATCH * 4);
  float* w_at = (float*)carve((size_t)DIM * BATCH * 4);
  float* w_ot = (float*)carve((size_t)DIM * BATCH * 4);
  float* w_qkp = (float*)carve((size_t)2 * BATCH * 3 * DIM * 4);
  float* w_aop = (float*)carve((size_t)2 * DIM * BATCH * 4);
  float* w_fcp = (float*)carve((size_t)2 * 4 * DIM * BATCH * 4);
  float* w_prp = (float*)carve((size_t)4 * DIM * BATCH * 4);
  float* w_logits = (float*)carve((size_t)BATCH * VOCAB * 4);

  const int M = BATCH * PROMPT_LEN;  // 1024
  const size_t kvstride = (size_t)BATCH * NHEAD * TMAX * HEADD;

  k_init<<<1, 256, 0, stream>>>(ids_in, mask_in, w_ids, w_lens, w_fin, w_csum, w_ccnt);
  k_embed_prefill<<<M, 256, 0, stream>>>(w_ids, wte, wpe, w_x);

  for (int l = 0; l < NLAYER; ++l) {
    float* kc = w_kc + (size_t)l * kvstride;
    float* vc = w_vc + (size_t)l * kvstride;
    k_layernorm<<<M, 256, 0, stream>>>(w_x, ln1_w + l * DIM, ln1_b + l * DIM, w_h);
    gemm_kernel<3><<<dim3(3 * DIM / 64, M / 64), 256, 0, stream>>>(
        w_h, qkv_w + (size_t)l * DIM * 3 * DIM, qkv_b + (size_t)l * 3 * DIM, nullptr, w_qkv, M,
        3 * DIM, DIM, kc, vc);
    k_attn_prefill<<<BATCH * NHEAD * PROMPT_LEN, 64, 0, stream>>>(w_qkv, kc, vc, w_att);
    gemm_kernel<2><<<dim3(DIM / 64, M / 64), 256, 0, stream>>>(
        w_att, ao_w + (size_t)l * DIM * DIM, ao_b + (size_t)l * DIM, w_x, w_x, M, DIM, DIM,
        nullptr, nullptr);
    k_layernorm<<<M, 256, 0, stream>>>(w_x, ln2_w + l * DIM, ln2_b + l * DIM, w_h);
    gemm_kernel<1><<<dim3(4 * DIM / 64, M / 64), 256, 0, stream>>>(
        w_h, fc_w + (size_t)l * DIM * 4 * DIM, fc_b + (size_t)l * 4 * DIM, nullptr, w_mlp, M,
        4 * DIM, DIM, nullptr, nullptr);
    gemm_kernel<2><<<dim3(DIM / 64, M / 64), 256, 0, stream>>>(
        w_mlp, pr_w + (size_t)l * 4 * DIM * DIM, pr_b + (size_t)l * DIM, w_x, w_x, M, DIM,
        4 * DIM, nullptr, nullptr);
  }

  k_embed0<<<BATCH, 256, 0, stream>>>(w_ids, w_lens, wte, wpe, w_xd0);

  for (int s = 0; s < NNEW; ++s) {
    for (int l = 0; l < NLAYER; ++l) {
      float* kc = w_kc + (size_t)l * kvstride;
      float* vc = w_vc + (size_t)l * kvstride;
      // QKV: ln1(xd) @ qkv_w -> 2 row-major partials [2][16][1536]
      if (l == 0) {
        k_skinny<2, SRC_LN, 0, 0, true, false, 3 * DIM, DIM>
            <<<dim3(24, 2), 512, 0, stream>>>(w_xd0, nullptr, ln1_w + l * DIM, ln1_b + l * DIM,
                                              qkv_b + (size_t)l * 3 * DIM,
                                              qkv_w + (size_t)l * DIM * 3 * DIM, w_qkp, nullptr);
      } else {
        // xd_in = xd1 + 4 pr partials; write xd0
        k_skinny<2, SRC_LN, 4, 0, true, true, 3 * DIM, DIM>
            <<<dim3(24, 2), 512, 0, stream>>>(w_xd1, w_prp, ln1_w + l * DIM, ln1_b + l * DIM,
                                              qkv_b + (size_t)l * 3 * DIM,
                                              qkv_w + (size_t)l * DIM * 3 * DIM, w_qkp, w_xd0);
      }
      // attention: sums 2 qkv partials, appends KV, Ot[512][16]
      k_attn_decode<<<BATCH * NHEAD, 64, 0, stream>>>(w_qkp, w_lens, kc, vc, w_ot);
      // AO: Ot @ ao_w -> 2 transposed partials [2][512][16]
      k_skinny<2, SRC_PLAIN, 0, 1, true, false, DIM, DIM><<<dim3(8, 2), 512, 0, stream>>>(
          w_ot, nullptr, nullptr, nullptr, ao_b + (size_t)l * DIM, ao_w + (size_t)l * DIM * DIM,
          w_aop, nullptr);
      // FC: ln2(xd0 + 2 ao partials) @ fc_w -> 2 transposed partials; write xd1
      k_skinny<2, SRC_LN, 2, 1, true, true, 4 * DIM, DIM><<<dim3(32, 2), 512, 0, stream>>>(
          w_xd0, w_aop, ln2_w + l * DIM, ln2_b + l * DIM, fc_b + (size_t)l * 4 * DIM,
          fc_w + (size_t)l * DIM * 4 * DIM, w_fcp, w_xd1);
      // PR: gelu(sum 2 fc partials) @ pr_w -> 4 transposed partials [4][512][16]
      k_skinny<4, SRC_GELU, 2, 1, true, false, DIM, 4 * DIM><<<dim3(8, 4), 512, 0, stream>>>(
          nullptr, w_fcp, nullptr, nullptr, pr_b + (size_t)l * DIM,
          pr_w + (size_t)l * 4 * DIM * DIM, w_prp, nullptr);
    }
    // final LN: At = lnf(xd1 + 4 pr partials)
    k_lnf<<<1, 512, 0, stream>>>(w_xd1, w_prp, lnf_w, lnf_b, w_at);
    // logits = At^T @ lm_w (row-major [16][8000])
    k_skinny<1, SRC_PLAIN, 0, 0, false, false, VOCAB, DIM><<<dim3(VOCAB / 64, 1), 512, 0, stream>>>(
        w_at, nullptr, nullptr, nullptr, nullptr, lm_w, w_logits, nullptr);
    // update state + embed next token -> xd0
    k_update<<<BATCH, 256, 0, stream>>>(w_logits, w_ids, w_lens, w_fin, w_csum, w_ccnt, out, s,
                                        wte, wpe, w_xd0);
  }
  k_finalize<<<1, 64, 0, stream>>>(w_csum, w_ccnt, out);
}